// Round 3
// baseline (571.254 us; speedup 1.0000x reference)
//
#include <hip/hip_runtime.h>

// PhaseMultiHeadAttention: B=8, N=1024, D=512, H=8, dh=64
// R13 = R12 + column-split flash blocks for 2x occupancy:
//   block = 2 waves on the SAME 32 rows; wave0 does K/V tiles t=0..7,
//   wave1 does t=8..15 (E-window carry generalized to arbitrary tstart).
//   Partial (o, rowsum) merged in LDS (Osum/Lsum + one barrier) -- no HBM
//   partials, no merge kernel. Grid 1024->2048 blocks = 8 blocks/CU =
//   4 waves/SIMD (launch_bounds(128,4), VGPR<=128). FETCH unchanged (~17MB);
//   goal is pure TLP: hide the per-half serial chain (MFMA->shuffle->exp->
//   LDS->PV) behind 2x more resident waves.
// rel[n,m] = Q[n] . E_rel[m-n+N-1]

typedef __bf16 bf16x8 __attribute__((ext_vector_type(8)));
typedef __bf16 bf16x4 __attribute__((ext_vector_type(4)));
typedef float  f32x4  __attribute__((ext_vector_type(4)));
typedef float  f32x16 __attribute__((ext_vector_type(16)));

#if __has_builtin(__builtin_amdgcn_exp2f)
#define EXP2(x) __builtin_amdgcn_exp2f(x)
#else
#define EXP2(x) exp2f(x)
#endif

#define QSCALE 0.18033688011f   // (1/8) * log2(e), folded into Q at projection

// async global->LDS, 16B per lane; LDS dest = wave-uniform base + lane*16
#define GLOAD_LDS16(g, l)                                                      \
    __builtin_amdgcn_global_load_lds(                                          \
        (const __attribute__((address_space(1))) unsigned int*)(g),            \
        (__attribute__((address_space(3))) unsigned int*)(l), 16, 0, 0)

// Fragment-stream layouts (per bh, 65536 elems = 128KB):
//  Kf: [t32 = n>>5][ks = d>>4][lane = ((d>>3)&1)*32 + (n&31)][j = d&7]
//  Vf: [t64 = n>>6][ks = (n>>4)&3][dhalf = d>>5][lane = ((n>>3)&1)*32 + (d&31)][j = n&7]
//  Ef: like Kf over 2048 rows (l = row index): [t32 = l>>5][ks][lane][j]

// ---------------- fused fp32 -> bf16 conversion ----------------
__global__ __launch_bounds__(256) void cvt_all(const float* __restrict__ x,
                                               const float* __restrict__ E,
                                               const float* __restrict__ wq,
                                               const float* __restrict__ wk,
                                               const float* __restrict__ wv,
                                               const float* __restrict__ wo,
                                               __bf16* __restrict__ xb,
                                               __bf16* __restrict__ Ef,
                                               __bf16* __restrict__ wqkv,
                                               __bf16* __restrict__ wob) {
    int i = blockIdx.x * 256 + threadIdx.x;
    if (i >= 1081328 ? i < 1343472 : i < 1048576) {
        const float* s; __bf16* d; int off;
        if      (i < 1048576) { s = x;  d = xb;            off = i; }
        else if (i < 1146864) { s = wq; d = wqkv;          off = i - 1081328; }
        else if (i < 1212400) { s = wk; d = wqkv + 262144; off = i - 1146864; }
        else if (i < 1277936) { s = wv; d = wqkv + 524288; off = i - 1212400; }
        else                  { s = wo; d = wob;           off = i - 1277936; }
        float4 v = *(const float4*)(s + (size_t)off * 4);
        bf16x4 o;
        o[0] = (__bf16)v.x; o[1] = (__bf16)v.y; o[2] = (__bf16)v.z; o[3] = (__bf16)v.w;
        *(bf16x4*)(d + (size_t)off * 4) = o;
    } else if (i >= 1048576 && i < 1081328) {
        // E -> fragment stream
        int off = i - 1048576;
        float4 v = *(const float4*)(E + (size_t)off * 4);
        int e0i = off * 4;
        int l = e0i >> 6, d0 = e0i & 63;
        int t32 = l >> 5, cq = l & 31, ks = d0 >> 4, hf = (d0 >> 3) & 1, j = d0 & 7;
        bf16x4 o;
        o[0] = (__bf16)v.x; o[1] = (__bf16)v.y; o[2] = (__bf16)v.z; o[3] = (__bf16)v.w;
        *(bf16x4*)(Ef + ((size_t)((t32 * 4 + ks) * 64) + hf * 32 + cq) * 8 + j) = o;
    }
}

// ---------------- QKV projection GEMM ----------------
__global__ __launch_bounds__(256) void gemm_qkv(const __bf16* __restrict__ X,
                                                const __bf16* __restrict__ W,
                                                __bf16* __restrict__ Qb,
                                                __bf16* __restrict__ Kf,
                                                __bf16* __restrict__ Vf) {
    __shared__ __bf16 Xs[128][64];
    __shared__ __bf16 Ws[128][64];
    const int tid = threadIdx.x;
    const int wave = tid >> 6, lane = tid & 63;
    const int col = lane & 15, quad = lane >> 4;
    const int m_base = blockIdx.x * 128;
    const int j_base = blockIdx.y * 128;
    const bool qk = (j_base < 1024);
    const int wm = (wave & 1) * 64;
    const int wn = (wave >> 1) * 64;
    const f32x4 fz = {0.f, 0.f, 0.f, 0.f};
    f32x4 acc[4][4];
#pragma unroll
    for (int i = 0; i < 4; ++i)
#pragma unroll
        for (int j = 0; j < 4; ++j) acc[i][j] = fz;

    for (int k0 = 0; k0 < 512; k0 += 64) {
#pragma unroll
        for (int p = 0; p < 4; ++p) {
            int s = tid + p * 256;
            int row = s >> 3, cc = (s & 7) * 8;
            GLOAD_LDS16(X + (size_t)(m_base + row) * 512 + k0 + cc, &Xs[0][0] + (size_t)s * 8);
            GLOAD_LDS16(W + (size_t)(j_base + row) * 512 + k0 + cc, &Ws[0][0] + (size_t)s * 8);
        }
        __syncthreads();
#pragma unroll
        for (int kk = 0; kk < 64; kk += 32) {
            bf16x8 xa[4], wb[4];
#pragma unroll
            for (int i = 0; i < 4; ++i) xa[i] = *(const bf16x8*)(&Xs[wm + i * 16 + col][kk + quad * 8]);
#pragma unroll
            for (int j = 0; j < 4; ++j) wb[j] = *(const bf16x8*)(&Ws[wn + j * 16 + col][kk + quad * 8]);
            if (qk) {
#pragma unroll
                for (int i = 0; i < 4; ++i)
#pragma unroll
                    for (int j = 0; j < 4; ++j)
                        acc[i][j] = __builtin_amdgcn_mfma_f32_16x16x32_bf16(wb[i], xa[j], acc[i][j], 0, 0, 0);
            } else {
#pragma unroll
                for (int i = 0; i < 4; ++i)
#pragma unroll
                    for (int j = 0; j < 4; ++j)
                        acc[i][j] = __builtin_amdgcn_mfma_f32_16x16x32_bf16(xa[i], wb[j], acc[i][j], 0, 0, 0);
            }
        }
        __syncthreads();
    }
    if (qk) {
#pragma unroll
        for (int i = 0; i < 4; ++i) {
#pragma unroll
            for (int j = 0; j < 4; ++j) {
                int jabs = j_base + wn + i * 16 + quad * 4;
                int m = m_base + wm + j * 16 + col;
                int b_ = m >> 10, n = m & 1023;
                int rem = jabs & 511, h = rem >> 6, d = rem & 63;
                bf16x4 v;
                if (jabs < 512) {
                    v[0] = (__bf16)(acc[i][j][0] * QSCALE);
                    v[1] = (__bf16)(acc[i][j][1] * QSCALE);
                    v[2] = (__bf16)(acc[i][j][2] * QSCALE);
                    v[3] = (__bf16)(acc[i][j][3] * QSCALE);
                    *(bf16x4*)(Qb + (((size_t)b_ * 8 + h) * 1024 + n) * 64 + d) = v;
                } else {
                    v[0] = (__bf16)acc[i][j][0]; v[1] = (__bf16)acc[i][j][1];
                    v[2] = (__bf16)acc[i][j][2]; v[3] = (__bf16)acc[i][j][3];
                    int t32 = n >> 5, cq = n & 31, ks = d >> 4, hf = (d >> 3) & 1, jj = d & 7;
                    *(bf16x4*)(Kf + (size_t)(b_ * 8 + h) * 65536 +
                               ((size_t)((t32 * 4 + ks) * 64) + hf * 32 + cq) * 8 + jj) = v;
                }
            }
        }
    } else {
#pragma unroll
        for (int i = 0; i < 4; ++i) {
#pragma unroll
            for (int j = 0; j < 4; ++j) {
                int m = m_base + wm + i * 16 + quad * 4;
                int b_ = m >> 10, n = m & 1023;
                int jabs = j_base + wn + j * 16 + col;
                int rem = jabs & 511, h = rem >> 6, d = rem & 63;
                int t64 = n >> 6, ks = (n >> 4) & 3, hf = (n >> 3) & 1, jj = n & 7;
                int dhalf = d >> 5, cq = d & 31;
                bf16x4 v;
                v[0] = (__bf16)acc[i][j][0]; v[1] = (__bf16)acc[i][j][1];
                v[2] = (__bf16)acc[i][j][2]; v[3] = (__bf16)acc[i][j][3];
                *(bf16x4*)(Vf + (size_t)(b_ * 8 + h) * 65536 +
                           ((size_t)(((t64 * 4 + ks) * 2 + dhalf) * 64) + hf * 32 + cq) * 8 + jj) = v;
            }
        }
    }
}

// ---------------- flash attention (column-split waves + LDS merge) ----------------
// grid: 2048 blocks (1-D, XCD-swizzled). 128 threads = 2 waves on the SAME
// 32 rows; wave w handles K/V tiles t = w*8 .. w*8+7, partials merged in LDS.
#define FLASH_HALF(T, KC0, KC1, KN0, KN1)                                              \
  {                                                                                    \
    const int t_ = (T);                                                                \
    const int teB_ = te0 + 2 * t_ + 1;                                                 \
    bf16x8 e1f[4], e2f[4], v0f[4], v1f[4];                                             \
    _Pragma("unroll")                                                                  \
    for (int ks = 0; ks < 4; ++ks) {                                                   \
      e1f[ks] = *(const bf16x8*)(Ef + ((size_t)((teB_ * 4 + ks) * 64) + lane) * 8);    \
      e2f[ks] = *(const bf16x8*)(Ef + ((size_t)(((teB_ + 1) * 4 + ks) * 64) + lane) * 8); \
    }                                                                                  \
    _Pragma("unroll")                                                                  \
    for (int ks = 0; ks < 4; ++ks) {                                                   \
      v0f[ks] = *(const bf16x8*)(Vfb + ((size_t)(((t_ * 4 + ks) * 2 + 0) * 64) + lane) * 8); \
      v1f[ks] = *(const bf16x8*)(Vfb + ((size_t)(((t_ * 4 + ks) * 2 + 1) * 64) + lane) * 8); \
    }                                                                                  \
    f32x16 qeB = z16, qeC = z16, s0 = z16, s1 = z16;                                   \
    _Pragma("unroll")                                                                  \
    for (int ks = 0; ks < 4; ++ks) {                                                   \
      s0 = __builtin_amdgcn_mfma_f32_32x32x16_bf16(a_q[ks], KC0[ks], s0, 0, 0, 0);     \
      s1 = __builtin_amdgcn_mfma_f32_32x32x16_bf16(a_q[ks], KC1[ks], s1, 0, 0, 0);     \
    }                                                                                  \
    const int t32n_ = (((T) + 1) & 15) * 2;                                            \
    _Pragma("unroll")                                                                  \
    for (int ks = 0; ks < 4; ++ks) {                                                   \
      KN0[ks] = *(const bf16x8*)(Kfb + ((size_t)((t32n_ * 4 + ks) * 64) + lane) * 8);  \
      KN1[ks] = *(const bf16x8*)(Kfb + ((size_t)(((t32n_ + 1) * 4 + ks) * 64) + lane) * 8); \
    }                                                                                  \
    _Pragma("unroll")                                                                  \
    for (int ks = 0; ks < 4; ++ks) {                                                   \
      qeB = __builtin_amdgcn_mfma_f32_32x32x16_bf16(a_q[ks], e1f[ks], qeB, 0, 0, 0);   \
      qeC = __builtin_amdgcn_mfma_f32_32x32x16_bf16(a_q[ks], e2f[ks], qeC, 0, 0, 0);   \
    }                                                                                  \
    _Pragma("unroll")                                                                  \
    for (int r = 0; r < 16; ++r) {                                                     \
      int row = (r & 3) + 8 * (r >> 2) + 4 * half;                                     \
      int tt = colq + 31 - row;                                                        \
      int src = (tt & 31) | (half << 5);                                               \
      float shB = __shfl(qeB[r], src, 64);                                             \
      float shC = __shfl(qeC[r], src, 64);                                             \
      bool sel = (tt >= 32);                                                           \
      float rel0 = sel ? shB : shA[r];                                                 \
      float rel1 = sel ? shC : shB;                                                    \
      float p0 = EXP2(s0[r] + rel0);                                                   \
      float p1 = EXP2(s1[r] + rel1);                                                   \
      rowsum[r] += p0 + p1;                                                            \
      Pw[w][row][colq]      = (__bf16)p0;                                              \
      Pw[w][row][32 + colq] = (__bf16)p1;                                              \
      shA[r] = shC;                                                                    \
    }                                                                                  \
    asm volatile("s_waitcnt lgkmcnt(0)" ::: "memory");                                 \
    _Pragma("unroll")                                                                  \
    for (int ks = 0; ks < 4; ++ks) {                                                   \
      bf16x8 pa = *(const bf16x8*)(&Pw[w][colq][ks * 16 + half * 8]);                  \
      o0 = __builtin_amdgcn_mfma_f32_32x32x16_bf16(pa, v0f[ks], o0, 0, 0, 0);          \
      o1 = __builtin_amdgcn_mfma_f32_32x32x16_bf16(pa, v1f[ks], o1, 0, 0, 0);          \
    }                                                                                  \
    asm volatile("" ::: "memory");                                                     \
  }

__global__ __launch_bounds__(128, 4) void flash_kernel(const __bf16* __restrict__ Qb,
                                                       const __bf16* __restrict__ Kf,
                                                       const __bf16* __restrict__ Vf,
                                                       const __bf16* __restrict__ Ef,
                                                       const float* __restrict__ phase,
                                                       __bf16* __restrict__ Ob) {
    // XCD-aware bijective swizzle (2048 blocks): wg&7 = XCD; each XCD owns
    // 8 bh values; all 32 row-tiles of a bh stay on one XCD's L2.
    const int wg = blockIdx.x;             // 0..2047
    const int xcd = wg & 7;
    const int slot = wg >> 3;              // 0..255
    const int bh = xcd * 8 + (slot >> 5);  // 0..63
    const int nbase = (slot & 31) * 32;    // 32-row tile
    const int w = threadIdx.x >> 6, lane = threadIdx.x & 63;
    const int colq = lane & 31, half = lane >> 5;
    const int tstart = w * 8;              // wave's K/V tile range: tstart..tstart+7

    __shared__ __bf16 Pw[2][32][72];   // per-wave P staging; conflict-free
    __shared__ float Osum[32][64];     // wave1 -> wave0 partial O
    __shared__ float Lsum[32];         // wave1 -> wave0 partial rowsum

    f32x16 z16;
#pragma unroll
    for (int i = 0; i < 16; ++i) z16[i] = 0.f;

    bf16x8 a_q[4];
#pragma unroll
    for (int ks = 0; ks < 4; ++ks)
        a_q[ks] = *(const bf16x8*)(Qb + ((size_t)bh * 1024 + nbase + colq) * 64 + ks * 16 + half * 8);

    f32x16 o0 = z16, o1 = z16;
    float rowsum[16];
#pragma unroll
    for (int i = 0; i < 16; ++i) rowsum[i] = 0.f;

    const __bf16* Kfb = Kf + (size_t)bh * 65536;
    const __bf16* Vfb = Vf + (size_t)bh * 65536;

    const int te0 = (992 - nbase) >> 5;   // first window tile of the row block
    const int teP = te0 + 2 * tstart;     // this wave's first window tile

    // K double-buffer register sets (this wave's first two tiles preloaded)
    bf16x8 kA0[4], kA1[4], kB0[4], kB1[4];
#pragma unroll
    for (int ks = 0; ks < 4; ++ks) {
        kA0[ks] = *(const bf16x8*)(Kfb + ((size_t)(((2 * tstart) * 4 + ks) * 64) + lane) * 8);
        kA1[ks] = *(const bf16x8*)(Kfb + ((size_t)(((2 * tstart + 1) * 4 + ks) * 64) + lane) * 8);
    }

    // prologue: shuffled values of tile teP (the carried "A" tile)
    float shA[16];
    {
        f32x16 qeA = z16;
#pragma unroll
        for (int ks = 0; ks < 4; ++ks) {
            bf16x8 e = *(const bf16x8*)(Ef + ((size_t)((teP * 4 + ks) * 64) + lane) * 8);
            qeA = __builtin_amdgcn_mfma_f32_32x32x16_bf16(a_q[ks], e, qeA, 0, 0, 0);
        }
#pragma unroll
        for (int r = 0; r < 16; ++r) {
            int row = (r & 3) + 8 * (r >> 2) + 4 * half;
            int tt = colq + 31 - row;
            int src = (tt & 31) | (half << 5);
            shA[r] = __shfl(qeA[r], src, 64);
        }
    }

#pragma unroll 1
    for (int tt2 = 0; tt2 < 4; ++tt2) {
        FLASH_HALF(tstart + 2 * tt2,     kA0, kA1, kB0, kB1)
        FLASH_HALF(tstart + 2 * tt2 + 1, kB0, kB1, kA0, kA1)
    }

    // per-wave rowsum reduce (result uniform across each 32-lane group)
#pragma unroll
    for (int r = 0; r < 16; ++r) {
        float l = rowsum[r];
        l += __shfl_xor(l, 1, 32);
        l += __shfl_xor(l, 2, 32);
        l += __shfl_xor(l, 4, 32);
        l += __shfl_xor(l, 8, 32);
        l += __shfl_xor(l, 16, 32);
        rowsum[r] = l;
    }

    // wave1 publishes partials; wave0 merges + does the epilogue
    if (w == 1) {
#pragma unroll
        for (int r = 0; r < 16; ++r) {
            int row = (r & 3) + 8 * (r >> 2) + 4 * half;
            Osum[row][colq]      = o0[r];
            Osum[row][32 + colq] = o1[r];
            if (colq == 0) Lsum[row] = rowsum[r];
        }
    }
    __syncthreads();
    if (w == 0) {
        const int b_ = bh >> 3, hh = bh & 7;
#pragma unroll
        for (int r = 0; r < 16; ++r) {
            int row = (r & 3) + 8 * (r >> 2) + 4 * half;
            float l = rowsum[r] + Lsum[row];
            float f = phase[(size_t)bh * 1024 + nbase + row] / l;
            float a0 = o0[r] + Osum[row][colq];
            float a1 = o1[r] + Osum[row][32 + colq];
            Pw[0][row][colq]      = (__bf16)(a0 * f);
            Pw[0][row][32 + colq] = (__bf16)(a1 * f);
        }
        asm volatile("s_waitcnt lgkmcnt(0)" ::: "memory");
        {
            int row = lane >> 1, dseg = lane & 1;
            bf16x8 u0 = *(const bf16x8*)(&Pw[0][row][dseg * 32]);
            bf16x8 u1 = *(const bf16x8*)(&Pw[0][row][dseg * 32 + 8]);
            bf16x8 u2 = *(const bf16x8*)(&Pw[0][row][dseg * 32 + 16]);
            bf16x8 u3 = *(const bf16x8*)(&Pw[0][row][dseg * 32 + 24]);
            size_t obase = ((size_t)b_ * 1024 + nbase + row) * 512 + hh * 64 + dseg * 32;
            *(bf16x8*)(Ob + obase)      = u0;
            *(bf16x8*)(Ob + obase + 8)  = u1;
            *(bf16x8*)(Ob + obase + 16) = u2;
            *(bf16x8*)(Ob + obase + 24) = u3;
        }
    }
}

// ---------------- output projection GEMM (128x64 tiles, 2 blocks/CU) ----------------
__global__ __launch_bounds__(256) void gemm_out(const __bf16* __restrict__ X,
                                                const __bf16* __restrict__ W,
                                                const float* __restrict__ bo,
                                                float* __restrict__ out) {
    __shared__ __bf16 Xs[128][64];
    __shared__ __bf16 Ws[64][64];
    const int tid = threadIdx.x;
    const int wave = tid >> 6, lane = tid & 63;
    const int col = lane & 15, quad = lane >> 4;
    const int m_base = blockIdx.x * 128;
    const int j_base = blockIdx.y * 64;
    const int wm = (wave & 1) * 64;
    const int wn = (wave >> 1) * 32;
    const f32x4 fz = {0.f, 0.f, 0.f, 0.f};
    f32x4 acc[2][4];
#pragma unroll
    for (int i = 0; i < 2; ++i)
#pragma unroll
        for (int j = 0; j < 4; ++j) acc[i][j] = fz;

    for (int k0 = 0; k0 < 512; k0 += 64) {
#pragma unroll
        for (int p = 0; p < 4; ++p) {
            int s = tid + p * 256;
            int row = s >> 3, cc = (s & 7) * 8;
            GLOAD_LDS16(X + (size_t)(m_base + row) * 512 + k0 + cc, &Xs[0][0] + (size_t)s * 8);
        }
#pragma unroll
        for (int p = 0; p < 2; ++p) {
            int s = tid + p * 256;
            int row = s >> 3, cc = (s & 7) * 8;
            GLOAD_LDS16(W + (size_t)(j_base + row) * 512 + k0 + cc, &Ws[0][0] + (size_t)s * 8);
        }
        __syncthreads();
#pragma unroll
        for (int kk = 0; kk < 64; kk += 32) {
            bf16x8 xa[4], wb[2];
#pragma unroll
            for (int j = 0; j < 4; ++j) xa[j] = *(const bf16x8*)(&Xs[wm + j * 16 + col][kk + quad * 8]);
#pragma unroll
            for (int i = 0; i < 2; ++i) wb[i] = *(const bf16x8*)(&Ws[wn + i * 16 + col][kk + quad * 8]);
#pragma unroll
            for (int i = 0; i < 2; ++i)
#pragma unroll
                for (int j = 0; j < 4; ++j)
                    acc[i][j] = __builtin_amdgcn_mfma_f32_16x16x32_bf16(wb[i], xa[j], acc[i][j], 0, 0, 0);
        }
        __syncthreads();
    }
#pragma unroll
    for (int i = 0; i < 2; ++i) {
#pragma unroll
        for (int j = 0; j < 4; ++j) {
            int jabs = j_base + wn + i * 16 + quad * 4;
            int m = m_base + wm + j * 16 + col;
            f32x4 bv = *(const f32x4*)(bo + jabs);
            f32x4 o = acc[i][j] + bv;
            *(f32x4*)(out + (size_t)m * 512 + jabs) = o;
        }
    }
}

extern "C" void kernel_launch(void* const* d_in, const int* in_sizes, int n_in,
                              void* d_out, int out_size, void* d_ws, size_t ws_size,
                              hipStream_t stream) {
    (void)in_sizes; (void)n_in; (void)out_size; (void)ws_size;
    const float* x     = (const float*)d_in[0];
    const float* phase = (const float*)d_in[1];
    const float* E_rel = (const float*)d_in[2];
    const float* W_q   = (const float*)d_in[3];
    const float* W_k   = (const float*)d_in[4];
    const float* W_v   = (const float*)d_in[5];
    const float* W_o   = (const float*)d_in[6];
    const float* b_o   = (const float*)d_in[7];
    float* out = (float*)d_out;

    char* ws = (char*)d_ws;
    __bf16* xb   = (__bf16*)(ws);                 //  8,388,608 B
    __bf16* wqkv = (__bf16*)(ws + 8388608);       //  1,572,864 B
    __bf16* wob  = (__bf16*)(ws + 9961472);       //    524,288 B
    __bf16* Ef   = (__bf16*)(ws + 10485760);      //    262,144 B fragment stream
    __bf16* Qb   = (__bf16*)(ws + 10747904);      //  8,388,608 B (pre-scaled)
    __bf16* Kf   = (__bf16*)(ws + 19136512);      //  8,388,608 B fragment stream
    __bf16* Vf   = (__bf16*)(ws + 27525120);      //  8,388,608 B fragment stream
    __bf16* Ob   = (__bf16*)(ws + 35913728);      //  8,388,608 B

    cvt_all<<<dim3(5249), dim3(256), 0, stream>>>(x, E_rel, W_q, W_k, W_v, W_o,
                                                  xb, Ef, wqkv, wob);
    gemm_qkv<<<dim3(64, 12), dim3(256), 0, stream>>>(xb, wqkv, Qb, Kf, Vf);
    flash_kernel<<<dim3(2048), dim3(128), 0, stream>>>(Qb, Kf, Vf, Ef, phase, Ob);
    gemm_out<<<dim3(64, 8), dim3(256), 0, stream>>>(Ob, wob, b_o, out);
}

// Round 4
// 199.148 us; speedup vs baseline: 2.8685x; 2.8685x over previous
//
#include <hip/hip_runtime.h>

// PhaseMultiHeadAttention: B=8, N=1024, D=512, H=8, dh=64
// R14 = R13 column-split flash, but launch_bounds back to (128,2):
//   R13's (128,4) made hipcc cap VGPR at 64 -> full spill to scratch
//   (WRITE_SIZE 846MB, 435us). At (128,2) the kernel compiles at ~128 VGPR
//   (proven in R12); the HW wave pool admits 16 waves/CU at VGPR=128, and
//   the 2048-block grid (8 blocks/CU) supplies them. Occupancy comes from
//   the grid + natural allocation, NOT from a forced allocator cap.
//   block = 2 waves on the SAME 32 rows; wave0 does K/V tiles t=0..7,
//   wave1 t=8..15; partials merged in LDS (no HBM partials, no merge kernel).
// rel[n,m] = Q[n] . E_rel[m-n+N-1]

typedef __bf16 bf16x8 __attribute__((ext_vector_type(8)));
typedef __bf16 bf16x4 __attribute__((ext_vector_type(4)));
typedef float  f32x4  __attribute__((ext_vector_type(4)));
typedef float  f32x16 __attribute__((ext_vector_type(16)));

#if __has_builtin(__builtin_amdgcn_exp2f)
#define EXP2(x) __builtin_amdgcn_exp2f(x)
#else
#define EXP2(x) exp2f(x)
#endif

#define QSCALE 0.18033688011f   // (1/8) * log2(e), folded into Q at projection

// async global->LDS, 16B per lane; LDS dest = wave-uniform base + lane*16
#define GLOAD_LDS16(g, l)                                                      \
    __builtin_amdgcn_global_load_lds(                                          \
        (const __attribute__((address_space(1))) unsigned int*)(g),            \
        (__attribute__((address_space(3))) unsigned int*)(l), 16, 0, 0)

// Fragment-stream layouts (per bh, 65536 elems = 128KB):
//  Kf: [t32 = n>>5][ks = d>>4][lane = ((d>>3)&1)*32 + (n&31)][j = d&7]
//  Vf: [t64 = n>>6][ks = (n>>4)&3][dhalf = d>>5][lane = ((n>>3)&1)*32 + (d&31)][j = n&7]
//  Ef: like Kf over 2048 rows (l = row index): [t32 = l>>5][ks][lane][j]

// ---------------- fused fp32 -> bf16 conversion ----------------
__global__ __launch_bounds__(256) void cvt_all(const float* __restrict__ x,
                                               const float* __restrict__ E,
                                               const float* __restrict__ wq,
                                               const float* __restrict__ wk,
                                               const float* __restrict__ wv,
                                               const float* __restrict__ wo,
                                               __bf16* __restrict__ xb,
                                               __bf16* __restrict__ Ef,
                                               __bf16* __restrict__ wqkv,
                                               __bf16* __restrict__ wob) {
    int i = blockIdx.x * 256 + threadIdx.x;
    if (i >= 1081328 ? i < 1343472 : i < 1048576) {
        const float* s; __bf16* d; int off;
        if      (i < 1048576) { s = x;  d = xb;            off = i; }
        else if (i < 1146864) { s = wq; d = wqkv;          off = i - 1081328; }
        else if (i < 1212400) { s = wk; d = wqkv + 262144; off = i - 1146864; }
        else if (i < 1277936) { s = wv; d = wqkv + 524288; off = i - 1212400; }
        else                  { s = wo; d = wob;           off = i - 1277936; }
        float4 v = *(const float4*)(s + (size_t)off * 4);
        bf16x4 o;
        o[0] = (__bf16)v.x; o[1] = (__bf16)v.y; o[2] = (__bf16)v.z; o[3] = (__bf16)v.w;
        *(bf16x4*)(d + (size_t)off * 4) = o;
    } else if (i >= 1048576 && i < 1081328) {
        // E -> fragment stream
        int off = i - 1048576;
        float4 v = *(const float4*)(E + (size_t)off * 4);
        int e0i = off * 4;
        int l = e0i >> 6, d0 = e0i & 63;
        int t32 = l >> 5, cq = l & 31, ks = d0 >> 4, hf = (d0 >> 3) & 1, j = d0 & 7;
        bf16x4 o;
        o[0] = (__bf16)v.x; o[1] = (__bf16)v.y; o[2] = (__bf16)v.z; o[3] = (__bf16)v.w;
        *(bf16x4*)(Ef + ((size_t)((t32 * 4 + ks) * 64) + hf * 32 + cq) * 8 + j) = o;
    }
}

// ---------------- QKV projection GEMM ----------------
__global__ __launch_bounds__(256) void gemm_qkv(const __bf16* __restrict__ X,
                                                const __bf16* __restrict__ W,
                                                __bf16* __restrict__ Qb,
                                                __bf16* __restrict__ Kf,
                                                __bf16* __restrict__ Vf) {
    __shared__ __bf16 Xs[128][64];
    __shared__ __bf16 Ws[128][64];
    const int tid = threadIdx.x;
    const int wave = tid >> 6, lane = tid & 63;
    const int col = lane & 15, quad = lane >> 4;
    const int m_base = blockIdx.x * 128;
    const int j_base = blockIdx.y * 128;
    const bool qk = (j_base < 1024);
    const int wm = (wave & 1) * 64;
    const int wn = (wave >> 1) * 64;
    const f32x4 fz = {0.f, 0.f, 0.f, 0.f};
    f32x4 acc[4][4];
#pragma unroll
    for (int i = 0; i < 4; ++i)
#pragma unroll
        for (int j = 0; j < 4; ++j) acc[i][j] = fz;

    for (int k0 = 0; k0 < 512; k0 += 64) {
#pragma unroll
        for (int p = 0; p < 4; ++p) {
            int s = tid + p * 256;
            int row = s >> 3, cc = (s & 7) * 8;
            GLOAD_LDS16(X + (size_t)(m_base + row) * 512 + k0 + cc, &Xs[0][0] + (size_t)s * 8);
            GLOAD_LDS16(W + (size_t)(j_base + row) * 512 + k0 + cc, &Ws[0][0] + (size_t)s * 8);
        }
        __syncthreads();
#pragma unroll
        for (int kk = 0; kk < 64; kk += 32) {
            bf16x8 xa[4], wb[4];
#pragma unroll
            for (int i = 0; i < 4; ++i) xa[i] = *(const bf16x8*)(&Xs[wm + i * 16 + col][kk + quad * 8]);
#pragma unroll
            for (int j = 0; j < 4; ++j) wb[j] = *(const bf16x8*)(&Ws[wn + j * 16 + col][kk + quad * 8]);
            if (qk) {
#pragma unroll
                for (int i = 0; i < 4; ++i)
#pragma unroll
                    for (int j = 0; j < 4; ++j)
                        acc[i][j] = __builtin_amdgcn_mfma_f32_16x16x32_bf16(wb[i], xa[j], acc[i][j], 0, 0, 0);
            } else {
#pragma unroll
                for (int i = 0; i < 4; ++i)
#pragma unroll
                    for (int j = 0; j < 4; ++j)
                        acc[i][j] = __builtin_amdgcn_mfma_f32_16x16x32_bf16(xa[i], wb[j], acc[i][j], 0, 0, 0);
            }
        }
        __syncthreads();
    }
    if (qk) {
#pragma unroll
        for (int i = 0; i < 4; ++i) {
#pragma unroll
            for (int j = 0; j < 4; ++j) {
                int jabs = j_base + wn + i * 16 + quad * 4;
                int m = m_base + wm + j * 16 + col;
                int b_ = m >> 10, n = m & 1023;
                int rem = jabs & 511, h = rem >> 6, d = rem & 63;
                bf16x4 v;
                if (jabs < 512) {
                    v[0] = (__bf16)(acc[i][j][0] * QSCALE);
                    v[1] = (__bf16)(acc[i][j][1] * QSCALE);
                    v[2] = (__bf16)(acc[i][j][2] * QSCALE);
                    v[3] = (__bf16)(acc[i][j][3] * QSCALE);
                    *(bf16x4*)(Qb + (((size_t)b_ * 8 + h) * 1024 + n) * 64 + d) = v;
                } else {
                    v[0] = (__bf16)acc[i][j][0]; v[1] = (__bf16)acc[i][j][1];
                    v[2] = (__bf16)acc[i][j][2]; v[3] = (__bf16)acc[i][j][3];
                    int t32 = n >> 5, cq = n & 31, ks = d >> 4, hf = (d >> 3) & 1, jj = d & 7;
                    *(bf16x4*)(Kf + (size_t)(b_ * 8 + h) * 65536 +
                               ((size_t)((t32 * 4 + ks) * 64) + hf * 32 + cq) * 8 + jj) = v;
                }
            }
        }
    } else {
#pragma unroll
        for (int i = 0; i < 4; ++i) {
#pragma unroll
            for (int j = 0; j < 4; ++j) {
                int m = m_base + wm + i * 16 + quad * 4;
                int b_ = m >> 10, n = m & 1023;
                int jabs = j_base + wn + j * 16 + col;
                int rem = jabs & 511, h = rem >> 6, d = rem & 63;
                int t64 = n >> 6, ks = (n >> 4) & 3, hf = (n >> 3) & 1, jj = n & 7;
                int dhalf = d >> 5, cq = d & 31;
                bf16x4 v;
                v[0] = (__bf16)acc[i][j][0]; v[1] = (__bf16)acc[i][j][1];
                v[2] = (__bf16)acc[i][j][2]; v[3] = (__bf16)acc[i][j][3];
                *(bf16x4*)(Vf + (size_t)(b_ * 8 + h) * 65536 +
                           ((size_t)(((t64 * 4 + ks) * 2 + dhalf) * 64) + hf * 32 + cq) * 8 + jj) = v;
            }
        }
    }
}

// ---------------- flash attention (column-split waves + LDS merge) ----------------
// grid: 2048 blocks (1-D, XCD-swizzled). 128 threads = 2 waves on the SAME
// 32 rows; wave w handles K/V tiles t = w*8 .. w*8+7, partials merged in LDS.
#define FLASH_HALF(T, KC0, KC1, KN0, KN1)                                              \
  {                                                                                    \
    const int t_ = (T);                                                                \
    const int teB_ = te0 + 2 * t_ + 1;                                                 \
    bf16x8 e1f[4], e2f[4], v0f[4], v1f[4];                                             \
    _Pragma("unroll")                                                                  \
    for (int ks = 0; ks < 4; ++ks) {                                                   \
      e1f[ks] = *(const bf16x8*)(Ef + ((size_t)((teB_ * 4 + ks) * 64) + lane) * 8);    \
      e2f[ks] = *(const bf16x8*)(Ef + ((size_t)(((teB_ + 1) * 4 + ks) * 64) + lane) * 8); \
    }                                                                                  \
    _Pragma("unroll")                                                                  \
    for (int ks = 0; ks < 4; ++ks) {                                                   \
      v0f[ks] = *(const bf16x8*)(Vfb + ((size_t)(((t_ * 4 + ks) * 2 + 0) * 64) + lane) * 8); \
      v1f[ks] = *(const bf16x8*)(Vfb + ((size_t)(((t_ * 4 + ks) * 2 + 1) * 64) + lane) * 8); \
    }                                                                                  \
    f32x16 qeB = z16, qeC = z16, s0 = z16, s1 = z16;                                   \
    _Pragma("unroll")                                                                  \
    for (int ks = 0; ks < 4; ++ks) {                                                   \
      s0 = __builtin_amdgcn_mfma_f32_32x32x16_bf16(a_q[ks], KC0[ks], s0, 0, 0, 0);     \
      s1 = __builtin_amdgcn_mfma_f32_32x32x16_bf16(a_q[ks], KC1[ks], s1, 0, 0, 0);     \
    }                                                                                  \
    const int t32n_ = (((T) + 1) & 15) * 2;                                            \
    _Pragma("unroll")                                                                  \
    for (int ks = 0; ks < 4; ++ks) {                                                   \
      KN0[ks] = *(const bf16x8*)(Kfb + ((size_t)((t32n_ * 4 + ks) * 64) + lane) * 8);  \
      KN1[ks] = *(const bf16x8*)(Kfb + ((size_t)(((t32n_ + 1) * 4 + ks) * 64) + lane) * 8); \
    }                                                                                  \
    _Pragma("unroll")                                                                  \
    for (int ks = 0; ks < 4; ++ks) {                                                   \
      qeB = __builtin_amdgcn_mfma_f32_32x32x16_bf16(a_q[ks], e1f[ks], qeB, 0, 0, 0);   \
      qeC = __builtin_amdgcn_mfma_f32_32x32x16_bf16(a_q[ks], e2f[ks], qeC, 0, 0, 0);   \
    }                                                                                  \
    _Pragma("unroll")                                                                  \
    for (int r = 0; r < 16; ++r) {                                                     \
      int row = (r & 3) + 8 * (r >> 2) + 4 * half;                                     \
      int tt = colq + 31 - row;                                                        \
      int src = (tt & 31) | (half << 5);                                               \
      float shB = __shfl(qeB[r], src, 64);                                             \
      float shC = __shfl(qeC[r], src, 64);                                             \
      bool sel = (tt >= 32);                                                           \
      float rel0 = sel ? shB : shA[r];                                                 \
      float rel1 = sel ? shC : shB;                                                    \
      float p0 = EXP2(s0[r] + rel0);                                                   \
      float p1 = EXP2(s1[r] + rel1);                                                   \
      rowsum[r] += p0 + p1;                                                            \
      Pw[w][row][colq]      = (__bf16)p0;                                              \
      Pw[w][row][32 + colq] = (__bf16)p1;                                              \
      shA[r] = shC;                                                                    \
    }                                                                                  \
    asm volatile("s_waitcnt lgkmcnt(0)" ::: "memory");                                 \
    _Pragma("unroll")                                                                  \
    for (int ks = 0; ks < 4; ++ks) {                                                   \
      bf16x8 pa = *(const bf16x8*)(&Pw[w][colq][ks * 16 + half * 8]);                  \
      o0 = __builtin_amdgcn_mfma_f32_32x32x16_bf16(pa, v0f[ks], o0, 0, 0, 0);          \
      o1 = __builtin_amdgcn_mfma_f32_32x32x16_bf16(pa, v1f[ks], o1, 0, 0, 0);          \
    }                                                                                  \
    asm volatile("" ::: "memory");                                                     \
  }

__global__ __launch_bounds__(128, 2) void flash_kernel(const __bf16* __restrict__ Qb,
                                                       const __bf16* __restrict__ Kf,
                                                       const __bf16* __restrict__ Vf,
                                                       const __bf16* __restrict__ Ef,
                                                       const float* __restrict__ phase,
                                                       __bf16* __restrict__ Ob) {
    // XCD-aware bijective swizzle (2048 blocks): wg&7 = XCD; each XCD owns
    // 8 bh values; all 32 row-tiles of a bh stay on one XCD's L2.
    const int wg = blockIdx.x;             // 0..2047
    const int xcd = wg & 7;
    const int slot = wg >> 3;              // 0..255
    const int bh = xcd * 8 + (slot >> 5);  // 0..63
    const int nbase = (slot & 31) * 32;    // 32-row tile
    const int w = threadIdx.x >> 6, lane = threadIdx.x & 63;
    const int colq = lane & 31, half = lane >> 5;
    const int tstart = w * 8;              // wave's K/V tile range: tstart..tstart+7

    __shared__ __bf16 Pw[2][32][72];   // per-wave P staging; conflict-free
    __shared__ float Osum[32][64];     // wave1 -> wave0 partial O
    __shared__ float Lsum[32];         // wave1 -> wave0 partial rowsum

    f32x16 z16;
#pragma unroll
    for (int i = 0; i < 16; ++i) z16[i] = 0.f;

    bf16x8 a_q[4];
#pragma unroll
    for (int ks = 0; ks < 4; ++ks)
        a_q[ks] = *(const bf16x8*)(Qb + ((size_t)bh * 1024 + nbase + colq) * 64 + ks * 16 + half * 8);

    f32x16 o0 = z16, o1 = z16;
    float rowsum[16];
#pragma unroll
    for (int i = 0; i < 16; ++i) rowsum[i] = 0.f;

    const __bf16* Kfb = Kf + (size_t)bh * 65536;
    const __bf16* Vfb = Vf + (size_t)bh * 65536;

    const int te0 = (992 - nbase) >> 5;   // first window tile of the row block
    const int teP = te0 + 2 * tstart;     // this wave's first window tile

    // K double-buffer register sets (this wave's first two tiles preloaded)
    bf16x8 kA0[4], kA1[4], kB0[4], kB1[4];
#pragma unroll
    for (int ks = 0; ks < 4; ++ks) {
        kA0[ks] = *(const bf16x8*)(Kfb + ((size_t)(((2 * tstart) * 4 + ks) * 64) + lane) * 8);
        kA1[ks] = *(const bf16x8*)(Kfb + ((size_t)(((2 * tstart + 1) * 4 + ks) * 64) + lane) * 8);
    }

    // prologue: shuffled values of tile teP (the carried "A" tile)
    float shA[16];
    {
        f32x16 qeA = z16;
#pragma unroll
        for (int ks = 0; ks < 4; ++ks) {
            bf16x8 e = *(const bf16x8*)(Ef + ((size_t)((teP * 4 + ks) * 64) + lane) * 8);
            qeA = __builtin_amdgcn_mfma_f32_32x32x16_bf16(a_q[ks], e, qeA, 0, 0, 0);
        }
#pragma unroll
        for (int r = 0; r < 16; ++r) {
            int row = (r & 3) + 8 * (r >> 2) + 4 * half;
            int tt = colq + 31 - row;
            int src = (tt & 31) | (half << 5);
            shA[r] = __shfl(qeA[r], src, 64);
        }
    }

#pragma unroll 1
    for (int tt2 = 0; tt2 < 4; ++tt2) {
        FLASH_HALF(tstart + 2 * tt2,     kA0, kA1, kB0, kB1)
        FLASH_HALF(tstart + 2 * tt2 + 1, kB0, kB1, kA0, kA1)
    }

    // per-wave rowsum reduce (result uniform across each 32-lane group)
#pragma unroll
    for (int r = 0; r < 16; ++r) {
        float l = rowsum[r];
        l += __shfl_xor(l, 1, 32);
        l += __shfl_xor(l, 2, 32);
        l += __shfl_xor(l, 4, 32);
        l += __shfl_xor(l, 8, 32);
        l += __shfl_xor(l, 16, 32);
        rowsum[r] = l;
    }

    // wave1 publishes partials; wave0 merges + does the epilogue
    if (w == 1) {
#pragma unroll
        for (int r = 0; r < 16; ++r) {
            int row = (r & 3) + 8 * (r >> 2) + 4 * half;
            Osum[row][colq]      = o0[r];
            Osum[row][32 + colq] = o1[r];
            if (colq == 0) Lsum[row] = rowsum[r];
        }
    }
    __syncthreads();
    if (w == 0) {
        const int b_ = bh >> 3, hh = bh & 7;
#pragma unroll
        for (int r = 0; r < 16; ++r) {
            int row = (r & 3) + 8 * (r >> 2) + 4 * half;
            float l = rowsum[r] + Lsum[row];
            float f = phase[(size_t)bh * 1024 + nbase + row] / l;
            float a0 = o0[r] + Osum[row][colq];
            float a1 = o1[r] + Osum[row][32 + colq];
            Pw[0][row][colq]      = (__bf16)(a0 * f);
            Pw[0][row][32 + colq] = (__bf16)(a1 * f);
        }
        asm volatile("s_waitcnt lgkmcnt(0)" ::: "memory");
        {
            int row = lane >> 1, dseg = lane & 1;
            bf16x8 u0 = *(const bf16x8*)(&Pw[0][row][dseg * 32]);
            bf16x8 u1 = *(const bf16x8*)(&Pw[0][row][dseg * 32 + 8]);
            bf16x8 u2 = *(const bf16x8*)(&Pw[0][row][dseg * 32 + 16]);
            bf16x8 u3 = *(const bf16x8*)(&Pw[0][row][dseg * 32 + 24]);
            size_t obase = ((size_t)b_ * 1024 + nbase + row) * 512 + hh * 64 + dseg * 32;
            *(bf16x8*)(Ob + obase)      = u0;
            *(bf16x8*)(Ob + obase + 8)  = u1;
            *(bf16x8*)(Ob + obase + 16) = u2;
            *(bf16x8*)(Ob + obase + 24) = u3;
        }
    }
}

// ---------------- output projection GEMM (128x64 tiles, 2 blocks/CU) ----------------
__global__ __launch_bounds__(256) void gemm_out(const __bf16* __restrict__ X,
                                                const __bf16* __restrict__ W,
                                                const float* __restrict__ bo,
                                                float* __restrict__ out) {
    __shared__ __bf16 Xs[128][64];
    __shared__ __bf16 Ws[64][64];
    const int tid = threadIdx.x;
    const int wave = tid >> 6, lane = tid & 63;
    const int col = lane & 15, quad = lane >> 4;
    const int m_base = blockIdx.x * 128;
    const int j_base = blockIdx.y * 64;
    const int wm = (wave & 1) * 64;
    const int wn = (wave >> 1) * 32;
    const f32x4 fz = {0.f, 0.f, 0.f, 0.f};
    f32x4 acc[2][4];
#pragma unroll
    for (int i = 0; i < 2; ++i)
#pragma unroll
        for (int j = 0; j < 4; ++j) acc[i][j] = fz;

    for (int k0 = 0; k0 < 512; k0 += 64) {
#pragma unroll
        for (int p = 0; p < 4; ++p) {
            int s = tid + p * 256;
            int row = s >> 3, cc = (s & 7) * 8;
            GLOAD_LDS16(X + (size_t)(m_base + row) * 512 + k0 + cc, &Xs[0][0] + (size_t)s * 8);
        }
#pragma unroll
        for (int p = 0; p < 2; ++p) {
            int s = tid + p * 256;
            int row = s >> 3, cc = (s & 7) * 8;
            GLOAD_LDS16(W + (size_t)(j_base + row) * 512 + k0 + cc, &Ws[0][0] + (size_t)s * 8);
        }
        __syncthreads();
#pragma unroll
        for (int kk = 0; kk < 64; kk += 32) {
            bf16x8 xa[4], wb[2];
#pragma unroll
            for (int j = 0; j < 4; ++j) xa[j] = *(const bf16x8*)(&Xs[wm + j * 16 + col][kk + quad * 8]);
#pragma unroll
            for (int i = 0; i < 2; ++i) wb[i] = *(const bf16x8*)(&Ws[wn + i * 16 + col][kk + quad * 8]);
#pragma unroll
            for (int i = 0; i < 2; ++i)
#pragma unroll
                for (int j = 0; j < 4; ++j)
                    acc[i][j] = __builtin_amdgcn_mfma_f32_16x16x32_bf16(wb[i], xa[j], acc[i][j], 0, 0, 0);
        }
        __syncthreads();
    }
#pragma unroll
    for (int i = 0; i < 2; ++i) {
#pragma unroll
        for (int j = 0; j < 4; ++j) {
            int jabs = j_base + wn + i * 16 + quad * 4;
            int m = m_base + wm + j * 16 + col;
            f32x4 bv = *(const f32x4*)(bo + jabs);
            f32x4 o = acc[i][j] + bv;
            *(f32x4*)(out + (size_t)m * 512 + jabs) = o;
        }
    }
}

extern "C" void kernel_launch(void* const* d_in, const int* in_sizes, int n_in,
                              void* d_out, int out_size, void* d_ws, size_t ws_size,
                              hipStream_t stream) {
    (void)in_sizes; (void)n_in; (void)out_size; (void)ws_size;
    const float* x     = (const float*)d_in[0];
    const float* phase = (const float*)d_in[1];
    const float* E_rel = (const float*)d_in[2];
    const float* W_q   = (const float*)d_in[3];
    const float* W_k   = (const float*)d_in[4];
    const float* W_v   = (const float*)d_in[5];
    const float* W_o   = (const float*)d_in[6];
    const float* b_o   = (const float*)d_in[7];
    float* out = (float*)d_out;

    char* ws = (char*)d_ws;
    __bf16* xb   = (__bf16*)(ws);                 //  8,388,608 B
    __bf16* wqkv = (__bf16*)(ws + 8388608);       //  1,572,864 B
    __bf16* wob  = (__bf16*)(ws + 9961472);       //    524,288 B
    __bf16* Ef   = (__bf16*)(ws + 10485760);      //    262,144 B fragment stream
    __bf16* Qb   = (__bf16*)(ws + 10747904);      //  8,388,608 B (pre-scaled)
    __bf16* Kf   = (__bf16*)(ws + 19136512);      //  8,388,608 B fragment stream
    __bf16* Vf   = (__bf16*)(ws + 27525120);      //  8,388,608 B fragment stream
    __bf16* Ob   = (__bf16*)(ws + 35913728);      //  8,388,608 B

    cvt_all<<<dim3(5249), dim3(256), 0, stream>>>(x, E_rel, W_q, W_k, W_v, W_o,
                                                  xb, Ef, wqkv, wob);
    gemm_qkv<<<dim3(64, 12), dim3(256), 0, stream>>>(xb, wqkv, Qb, Kf, Vf);
    flash_kernel<<<dim3(2048), dim3(128), 0, stream>>>(Qb, Kf, Vf, Ef, phase, Ob);
    gemm_out<<<dim3(64, 8), dim3(256), 0, stream>>>(Ob, wob, b_o, out);
}

// Round 5
// 193.672 us; speedup vs baseline: 2.9496x; 1.0283x over previous
//
#include <hip/hip_runtime.h>

// PhaseMultiHeadAttention: B=8, N=1024, D=512, H=8, dh=64
// R15 = R11-exact flash (proven best: 55.6us) + T5 s_setprio around MFMA
// clusters. R13/R14 post-mortem: the col-split occupancy play is excluded --
// per-wave state needs >128 unified VGPR+AGPR, and the HW occupancy quantum
// (waves halve at 64/128/256 regs) pins this structure at 2 waves/SIMD.
// R12's XCD swizzle cut FETCH 4x but cost +2.2us -> reverted to 2D grid.
// setprio(1) wraps QK/QE/PV MFMA clusters, prio 0 through shuffle/exp/LDS:
// with 2 independent waves per block at different phases (no main-loop
// barrier), the CU scheduler favors the MFMA-phase wave (m191: +4-7%).
// rel[n,m] = Q[n] . E_rel[m-n+N-1]

typedef __bf16 bf16x8 __attribute__((ext_vector_type(8)));
typedef __bf16 bf16x4 __attribute__((ext_vector_type(4)));
typedef float  f32x4  __attribute__((ext_vector_type(4)));
typedef float  f32x16 __attribute__((ext_vector_type(16)));

#if __has_builtin(__builtin_amdgcn_exp2f)
#define EXP2(x) __builtin_amdgcn_exp2f(x)
#else
#define EXP2(x) exp2f(x)
#endif

#define QSCALE 0.18033688011f   // (1/8) * log2(e), folded into Q at projection

// async global->LDS, 16B per lane; LDS dest = wave-uniform base + lane*16
#define GLOAD_LDS16(g, l)                                                      \
    __builtin_amdgcn_global_load_lds(                                          \
        (const __attribute__((address_space(1))) unsigned int*)(g),            \
        (__attribute__((address_space(3))) unsigned int*)(l), 16, 0, 0)

// Fragment-stream layouts (per bh, 65536 elems = 128KB):
//  Kf: [t32 = n>>5][ks = d>>4][lane = ((d>>3)&1)*32 + (n&31)][j = d&7]
//  Vf: [t64 = n>>6][ks = (n>>4)&3][dhalf = d>>5][lane = ((n>>3)&1)*32 + (d&31)][j = n&7]
//  Ef: like Kf over 2048 rows (l = row index): [t32 = l>>5][ks][lane][j]

// ---------------- fused fp32 -> bf16 conversion ----------------
__global__ __launch_bounds__(256) void cvt_all(const float* __restrict__ x,
                                               const float* __restrict__ E,
                                               const float* __restrict__ wq,
                                               const float* __restrict__ wk,
                                               const float* __restrict__ wv,
                                               const float* __restrict__ wo,
                                               __bf16* __restrict__ xb,
                                               __bf16* __restrict__ Ef,
                                               __bf16* __restrict__ wqkv,
                                               __bf16* __restrict__ wob) {
    int i = blockIdx.x * 256 + threadIdx.x;
    if (i >= 1081328 ? i < 1343472 : i < 1048576) {
        const float* s; __bf16* d; int off;
        if      (i < 1048576) { s = x;  d = xb;            off = i; }
        else if (i < 1146864) { s = wq; d = wqkv;          off = i - 1081328; }
        else if (i < 1212400) { s = wk; d = wqkv + 262144; off = i - 1146864; }
        else if (i < 1277936) { s = wv; d = wqkv + 524288; off = i - 1212400; }
        else                  { s = wo; d = wob;           off = i - 1277936; }
        float4 v = *(const float4*)(s + (size_t)off * 4);
        bf16x4 o;
        o[0] = (__bf16)v.x; o[1] = (__bf16)v.y; o[2] = (__bf16)v.z; o[3] = (__bf16)v.w;
        *(bf16x4*)(d + (size_t)off * 4) = o;
    } else if (i >= 1048576 && i < 1081328) {
        // E -> fragment stream
        int off = i - 1048576;
        float4 v = *(const float4*)(E + (size_t)off * 4);
        int e0i = off * 4;
        int l = e0i >> 6, d0 = e0i & 63;
        int t32 = l >> 5, cq = l & 31, ks = d0 >> 4, hf = (d0 >> 3) & 1, j = d0 & 7;
        bf16x4 o;
        o[0] = (__bf16)v.x; o[1] = (__bf16)v.y; o[2] = (__bf16)v.z; o[3] = (__bf16)v.w;
        *(bf16x4*)(Ef + ((size_t)((t32 * 4 + ks) * 64) + hf * 32 + cq) * 8 + j) = o;
    }
}

// ---------------- QKV projection GEMM ----------------
__global__ __launch_bounds__(256) void gemm_qkv(const __bf16* __restrict__ X,
                                                const __bf16* __restrict__ W,
                                                __bf16* __restrict__ Qb,
                                                __bf16* __restrict__ Kf,
                                                __bf16* __restrict__ Vf) {
    __shared__ __bf16 Xs[128][64];
    __shared__ __bf16 Ws[128][64];
    const int tid = threadIdx.x;
    const int wave = tid >> 6, lane = tid & 63;
    const int col = lane & 15, quad = lane >> 4;
    const int m_base = blockIdx.x * 128;
    const int j_base = blockIdx.y * 128;
    const bool qk = (j_base < 1024);
    const int wm = (wave & 1) * 64;
    const int wn = (wave >> 1) * 64;
    const f32x4 fz = {0.f, 0.f, 0.f, 0.f};
    f32x4 acc[4][4];
#pragma unroll
    for (int i = 0; i < 4; ++i)
#pragma unroll
        for (int j = 0; j < 4; ++j) acc[i][j] = fz;

    for (int k0 = 0; k0 < 512; k0 += 64) {
#pragma unroll
        for (int p = 0; p < 4; ++p) {
            int s = tid + p * 256;
            int row = s >> 3, cc = (s & 7) * 8;
            GLOAD_LDS16(X + (size_t)(m_base + row) * 512 + k0 + cc, &Xs[0][0] + (size_t)s * 8);
            GLOAD_LDS16(W + (size_t)(j_base + row) * 512 + k0 + cc, &Ws[0][0] + (size_t)s * 8);
        }
        __syncthreads();
#pragma unroll
        for (int kk = 0; kk < 64; kk += 32) {
            bf16x8 xa[4], wb[4];
#pragma unroll
            for (int i = 0; i < 4; ++i) xa[i] = *(const bf16x8*)(&Xs[wm + i * 16 + col][kk + quad * 8]);
#pragma unroll
            for (int j = 0; j < 4; ++j) wb[j] = *(const bf16x8*)(&Ws[wn + j * 16 + col][kk + quad * 8]);
            if (qk) {
#pragma unroll
                for (int i = 0; i < 4; ++i)
#pragma unroll
                    for (int j = 0; j < 4; ++j)
                        acc[i][j] = __builtin_amdgcn_mfma_f32_16x16x32_bf16(wb[i], xa[j], acc[i][j], 0, 0, 0);
            } else {
#pragma unroll
                for (int i = 0; i < 4; ++i)
#pragma unroll
                    for (int j = 0; j < 4; ++j)
                        acc[i][j] = __builtin_amdgcn_mfma_f32_16x16x32_bf16(xa[i], wb[j], acc[i][j], 0, 0, 0);
            }
        }
        __syncthreads();
    }
    if (qk) {
#pragma unroll
        for (int i = 0; i < 4; ++i) {
#pragma unroll
            for (int j = 0; j < 4; ++j) {
                int jabs = j_base + wn + i * 16 + quad * 4;
                int m = m_base + wm + j * 16 + col;
                int b_ = m >> 10, n = m & 1023;
                int rem = jabs & 511, h = rem >> 6, d = rem & 63;
                bf16x4 v;
                if (jabs < 512) {
                    v[0] = (__bf16)(acc[i][j][0] * QSCALE);
                    v[1] = (__bf16)(acc[i][j][1] * QSCALE);
                    v[2] = (__bf16)(acc[i][j][2] * QSCALE);
                    v[3] = (__bf16)(acc[i][j][3] * QSCALE);
                    *(bf16x4*)(Qb + (((size_t)b_ * 8 + h) * 1024 + n) * 64 + d) = v;
                } else {
                    v[0] = (__bf16)acc[i][j][0]; v[1] = (__bf16)acc[i][j][1];
                    v[2] = (__bf16)acc[i][j][2]; v[3] = (__bf16)acc[i][j][3];
                    int t32 = n >> 5, cq = n & 31, ks = d >> 4, hf = (d >> 3) & 1, jj = d & 7;
                    *(bf16x4*)(Kf + (size_t)(b_ * 8 + h) * 65536 +
                               ((size_t)((t32 * 4 + ks) * 64) + hf * 32 + cq) * 8 + jj) = v;
                }
            }
        }
    } else {
#pragma unroll
        for (int i = 0; i < 4; ++i) {
#pragma unroll
            for (int j = 0; j < 4; ++j) {
                int m = m_base + wm + i * 16 + quad * 4;
                int b_ = m >> 10, n = m & 1023;
                int jabs = j_base + wn + j * 16 + col;
                int rem = jabs & 511, h = rem >> 6, d = rem & 63;
                int t64 = n >> 6, ks = (n >> 4) & 3, hf = (n >> 3) & 1, jj = n & 7;
                int dhalf = d >> 5, cq = d & 31;
                bf16x4 v;
                v[0] = (__bf16)acc[i][j][0]; v[1] = (__bf16)acc[i][j][1];
                v[2] = (__bf16)acc[i][j][2]; v[3] = (__bf16)acc[i][j][3];
                *(bf16x4*)(Vf + (size_t)(b_ * 8 + h) * 65536 +
                           ((size_t)(((t64 * 4 + ks) * 2 + dhalf) * 64) + hf * 32 + cq) * 8 + jj) = v;
            }
        }
    }
}

// ---------------- flash attention (R11 shell + setprio) ----------------
// grid: x = 16 (64-row n-tiles), y = 64 (b*h). 128 threads = 2 waves, 32 rows
// each, independent (no main-loop barrier) -> setprio arbitration pays.
#define FLASH_HALF(T, KC0, KC1, KN0, KN1)                                              \
  {                                                                                    \
    const int t_ = (T);                                                                \
    const int teB_ = te0 + 2 * t_ + 1;                                                 \
    bf16x8 e1f[4], e2f[4], v0f[4], v1f[4];                                             \
    _Pragma("unroll")                                                                  \
    for (int ks = 0; ks < 4; ++ks) {                                                   \
      e1f[ks] = *(const bf16x8*)(Ef + ((size_t)((teB_ * 4 + ks) * 64) + lane) * 8);    \
      e2f[ks] = *(const bf16x8*)(Ef + ((size_t)(((teB_ + 1) * 4 + ks) * 64) + lane) * 8); \
    }                                                                                  \
    _Pragma("unroll")                                                                  \
    for (int ks = 0; ks < 4; ++ks) {                                                   \
      v0f[ks] = *(const bf16x8*)(Vfb + ((size_t)(((t_ * 4 + ks) * 2 + 0) * 64) + lane) * 8); \
      v1f[ks] = *(const bf16x8*)(Vfb + ((size_t)(((t_ * 4 + ks) * 2 + 1) * 64) + lane) * 8); \
    }                                                                                  \
    f32x16 qeB = z16, qeC = z16, s0 = z16, s1 = z16;                                   \
    __builtin_amdgcn_s_setprio(1);                                                     \
    _Pragma("unroll")                                                                  \
    for (int ks = 0; ks < 4; ++ks) {                                                   \
      s0 = __builtin_amdgcn_mfma_f32_32x32x16_bf16(a_q[ks], KC0[ks], s0, 0, 0, 0);     \
      s1 = __builtin_amdgcn_mfma_f32_32x32x16_bf16(a_q[ks], KC1[ks], s1, 0, 0, 0);     \
    }                                                                                  \
    __builtin_amdgcn_s_setprio(0);                                                     \
    const int t32n_ = (((T) + 1) & 15) * 2;                                            \
    _Pragma("unroll")                                                                  \
    for (int ks = 0; ks < 4; ++ks) {                                                   \
      KN0[ks] = *(const bf16x8*)(Kfb + ((size_t)((t32n_ * 4 + ks) * 64) + lane) * 8);  \
      KN1[ks] = *(const bf16x8*)(Kfb + ((size_t)(((t32n_ + 1) * 4 + ks) * 64) + lane) * 8); \
    }                                                                                  \
    __builtin_amdgcn_s_setprio(1);                                                     \
    _Pragma("unroll")                                                                  \
    for (int ks = 0; ks < 4; ++ks) {                                                   \
      qeB = __builtin_amdgcn_mfma_f32_32x32x16_bf16(a_q[ks], e1f[ks], qeB, 0, 0, 0);   \
      qeC = __builtin_amdgcn_mfma_f32_32x32x16_bf16(a_q[ks], e2f[ks], qeC, 0, 0, 0);   \
    }                                                                                  \
    __builtin_amdgcn_s_setprio(0);                                                     \
    _Pragma("unroll")                                                                  \
    for (int r = 0; r < 16; ++r) {                                                     \
      int row = (r & 3) + 8 * (r >> 2) + 4 * half;                                     \
      int tt = colq + 31 - row;                                                        \
      int src = (tt & 31) | (half << 5);                                               \
      float shB = __shfl(qeB[r], src, 64);                                             \
      float shC = __shfl(qeC[r], src, 64);                                             \
      bool sel = (tt >= 32);                                                           \
      float rel0 = sel ? shB : shA[r];                                                 \
      float rel1 = sel ? shC : shB;                                                    \
      float p0 = EXP2(s0[r] + rel0);                                                   \
      float p1 = EXP2(s1[r] + rel1);                                                   \
      rowsum[r] += p0 + p1;                                                            \
      Pw[w][row][colq]      = (__bf16)p0;                                              \
      Pw[w][row][32 + colq] = (__bf16)p1;                                              \
      shA[r] = shC;                                                                    \
    }                                                                                  \
    asm volatile("s_waitcnt lgkmcnt(0)" ::: "memory");                                 \
    __builtin_amdgcn_s_setprio(1);                                                     \
    _Pragma("unroll")                                                                  \
    for (int ks = 0; ks < 4; ++ks) {                                                   \
      bf16x8 pa = *(const bf16x8*)(&Pw[w][colq][ks * 16 + half * 8]);                  \
      o0 = __builtin_amdgcn_mfma_f32_32x32x16_bf16(pa, v0f[ks], o0, 0, 0, 0);          \
      o1 = __builtin_amdgcn_mfma_f32_32x32x16_bf16(pa, v1f[ks], o1, 0, 0, 0);          \
    }                                                                                  \
    __builtin_amdgcn_s_setprio(0);                                                     \
    asm volatile("" ::: "memory");                                                     \
  }

__global__ __launch_bounds__(128, 2) void flash_kernel(const __bf16* __restrict__ Qb,
                                                       const __bf16* __restrict__ Kf,
                                                       const __bf16* __restrict__ Vf,
                                                       const __bf16* __restrict__ Ef,
                                                       const float* __restrict__ phase,
                                                       __bf16* __restrict__ Ob) {
    const int bh = blockIdx.y;
    const int n0 = blockIdx.x * 64;
    const int w = threadIdx.x >> 6, lane = threadIdx.x & 63;
    const int colq = lane & 31, half = lane >> 5;
    const int nbase = n0 + w * 32;

    __shared__ __bf16 Pw[2][32][72];   // per-wave P staging; conflict-free

    f32x16 z16;
#pragma unroll
    for (int i = 0; i < 16; ++i) z16[i] = 0.f;

    bf16x8 a_q[4];
#pragma unroll
    for (int ks = 0; ks < 4; ++ks)
        a_q[ks] = *(const bf16x8*)(Qb + ((size_t)bh * 1024 + nbase + colq) * 64 + ks * 16 + half * 8);

    f32x16 o0 = z16, o1 = z16;
    float rowsum[16];
#pragma unroll
    for (int i = 0; i < 16; ++i) rowsum[i] = 0.f;

    const __bf16* Kfb = Kf + (size_t)bh * 65536;
    const __bf16* Vfb = Vf + (size_t)bh * 65536;

    const int te0 = (992 - nbase) >> 5;   // first window tile (>= 0)

    // K double-buffer register sets (t=0 tiles preloaded here)
    bf16x8 kA0[4], kA1[4], kB0[4], kB1[4];
#pragma unroll
    for (int ks = 0; ks < 4; ++ks) {
        kA0[ks] = *(const bf16x8*)(Kfb + ((size_t)((0 * 4 + ks) * 64) + lane) * 8);
        kA1[ks] = *(const bf16x8*)(Kfb + ((size_t)((1 * 4 + ks) * 64) + lane) * 8);
    }

    // prologue: shuffled values of tile te0 (the carried "A" tile)
    float shA[16];
    {
        f32x16 qeA = z16;
#pragma unroll
        for (int ks = 0; ks < 4; ++ks) {
            bf16x8 e = *(const bf16x8*)(Ef + ((size_t)((te0 * 4 + ks) * 64) + lane) * 8);
            qeA = __builtin_amdgcn_mfma_f32_32x32x16_bf16(a_q[ks], e, qeA, 0, 0, 0);
        }
#pragma unroll
        for (int r = 0; r < 16; ++r) {
            int row = (r & 3) + 8 * (r >> 2) + 4 * half;
            int tt = colq + 31 - row;
            int src = (tt & 31) | (half << 5);
            shA[r] = __shfl(qeA[r], src, 64);
        }
    }

#pragma unroll 1
    for (int tt2 = 0; tt2 < 8; ++tt2) {
        FLASH_HALF(2 * tt2,     kA0, kA1, kB0, kB1)
        FLASH_HALF(2 * tt2 + 1, kB0, kB1, kA0, kA1)
    }

    // epilogue: l reduce, scale by phase/l, store via Pw for coalescing
    const int b_ = bh >> 3, hh = bh & 7;
#pragma unroll
    for (int r = 0; r < 16; ++r) {
        float l = rowsum[r];
        l += __shfl_xor(l, 1, 32);
        l += __shfl_xor(l, 2, 32);
        l += __shfl_xor(l, 4, 32);
        l += __shfl_xor(l, 8, 32);
        l += __shfl_xor(l, 16, 32);
        int row = (r & 3) + 8 * (r >> 2) + 4 * half;
        float f = phase[(size_t)bh * 1024 + nbase + row] / l;
        Pw[w][row][colq]      = (__bf16)(o0[r] * f);
        Pw[w][row][32 + colq] = (__bf16)(o1[r] * f);
    }
    asm volatile("s_waitcnt lgkmcnt(0)" ::: "memory");
    {
        int row = lane >> 1, dseg = lane & 1;
        bf16x8 u0 = *(const bf16x8*)(&Pw[w][row][dseg * 32]);
        bf16x8 u1 = *(const bf16x8*)(&Pw[w][row][dseg * 32 + 8]);
        bf16x8 u2 = *(const bf16x8*)(&Pw[w][row][dseg * 32 + 16]);
        bf16x8 u3 = *(const bf16x8*)(&Pw[w][row][dseg * 32 + 24]);
        size_t obase = ((size_t)b_ * 1024 + nbase + row) * 512 + hh * 64 + dseg * 32;
        *(bf16x8*)(Ob + obase)      = u0;
        *(bf16x8*)(Ob + obase + 8)  = u1;
        *(bf16x8*)(Ob + obase + 16) = u2;
        *(bf16x8*)(Ob + obase + 24) = u3;
    }
}

// ---------------- output projection GEMM (128x64 tiles, 2 blocks/CU) ----------------
__global__ __launch_bounds__(256) void gemm_out(const __bf16* __restrict__ X,
                                                const __bf16* __restrict__ W,
                                                const float* __restrict__ bo,
                                                float* __restrict__ out) {
    __shared__ __bf16 Xs[128][64];
    __shared__ __bf16 Ws[64][64];
    const int tid = threadIdx.x;
    const int wave = tid >> 6, lane = tid & 63;
    const int col = lane & 15, quad = lane >> 4;
    const int m_base = blockIdx.x * 128;
    const int j_base = blockIdx.y * 64;
    const int wm = (wave & 1) * 64;
    const int wn = (wave >> 1) * 32;
    const f32x4 fz = {0.f, 0.f, 0.f, 0.f};
    f32x4 acc[2][4];
#pragma unroll
    for (int i = 0; i < 2; ++i)
#pragma unroll
        for (int j = 0; j < 4; ++j) acc[i][j] = fz;

    for (int k0 = 0; k0 < 512; k0 += 64) {
#pragma unroll
        for (int p = 0; p < 4; ++p) {
            int s = tid + p * 256;
            int row = s >> 3, cc = (s & 7) * 8;
            GLOAD_LDS16(X + (size_t)(m_base + row) * 512 + k0 + cc, &Xs[0][0] + (size_t)s * 8);
        }
#pragma unroll
        for (int p = 0; p < 2; ++p) {
            int s = tid + p * 256;
            int row = s >> 3, cc = (s & 7) * 8;
            GLOAD_LDS16(W + (size_t)(j_base + row) * 512 + k0 + cc, &Ws[0][0] + (size_t)s * 8);
        }
        __syncthreads();
#pragma unroll
        for (int kk = 0; kk < 64; kk += 32) {
            bf16x8 xa[4], wb[2];
#pragma unroll
            for (int j = 0; j < 4; ++j) xa[j] = *(const bf16x8*)(&Xs[wm + j * 16 + col][kk + quad * 8]);
#pragma unroll
            for (int i = 0; i < 2; ++i) wb[i] = *(const bf16x8*)(&Ws[wn + i * 16 + col][kk + quad * 8]);
#pragma unroll
            for (int i = 0; i < 2; ++i)
#pragma unroll
                for (int j = 0; j < 4; ++j)
                    acc[i][j] = __builtin_amdgcn_mfma_f32_16x16x32_bf16(wb[i], xa[j], acc[i][j], 0, 0, 0);
        }
        __syncthreads();
    }
#pragma unroll
    for (int i = 0; i < 2; ++i) {
#pragma unroll
        for (int j = 0; j < 4; ++j) {
            int jabs = j_base + wn + i * 16 + quad * 4;
            int m = m_base + wm + j * 16 + col;
            f32x4 bv = *(const f32x4*)(bo + jabs);
            f32x4 o = acc[i][j] + bv;
            *(f32x4*)(out + (size_t)m * 512 + jabs) = o;
        }
    }
}

extern "C" void kernel_launch(void* const* d_in, const int* in_sizes, int n_in,
                              void* d_out, int out_size, void* d_ws, size_t ws_size,
                              hipStream_t stream) {
    (void)in_sizes; (void)n_in; (void)out_size; (void)ws_size;
    const float* x     = (const float*)d_in[0];
    const float* phase = (const float*)d_in[1];
    const float* E_rel = (const float*)d_in[2];
    const float* W_q   = (const float*)d_in[3];
    const float* W_k   = (const float*)d_in[4];
    const float* W_v   = (const float*)d_in[5];
    const float* W_o   = (const float*)d_in[6];
    const float* b_o   = (const float*)d_in[7];
    float* out = (float*)d_out;

    char* ws = (char*)d_ws;
    __bf16* xb   = (__bf16*)(ws);                 //  8,388,608 B
    __bf16* wqkv = (__bf16*)(ws + 8388608);       //  1,572,864 B
    __bf16* wob  = (__bf16*)(ws + 9961472);       //    524,288 B
    __bf16* Ef   = (__bf16*)(ws + 10485760);      //    262,144 B fragment stream
    __bf16* Qb   = (__bf16*)(ws + 10747904);      //  8,388,608 B (pre-scaled)
    __bf16* Kf   = (__bf16*)(ws + 19136512);      //  8,388,608 B fragment stream
    __bf16* Vf   = (__bf16*)(ws + 27525120);      //  8,388,608 B fragment stream
    __bf16* Ob   = (__bf16*)(ws + 35913728);      //  8,388,608 B

    cvt_all<<<dim3(5249), dim3(256), 0, stream>>>(x, E_rel, W_q, W_k, W_v, W_o,
                                                  xb, Ef, wqkv, wob);
    gemm_qkv<<<dim3(64, 12), dim3(256), 0, stream>>>(xb, wqkv, Qb, Kf, Vf);
    flash_kernel<<<dim3(16, 64), dim3(128), 0, stream>>>(Qb, Kf, Vf, Ef, phase, Ob);
    gemm_out<<<dim3(64, 8), dim3(256), 0, stream>>>(Ob, wob, b_o, out);
}

// Round 6
// 181.408 us; speedup vs baseline: 3.1490x; 1.0676x over previous
//
#include <hip/hip_runtime.h>

// PhaseMultiHeadAttention: B=8, N=1024, D=512, H=8, dh=64
// R16 = R11-exact flash (proven 55.6us; R15's setprio caused scratch spill
// via sched-region live-range extension -> reverted) + T3-minimum 2-phase
// pipeline on BOTH GEMMs:
//   double-buffered LDS; stage tile t+1 BEFORE computing tile t; raw
//   s_barrier + counted s_waitcnt vmcnt(N) (16 qkv / 6 out; 0 only on the
//   final iteration) so next-tile global_load_lds stay in flight across the
//   barrier instead of the __syncthreads vmcnt(0) drain every K-step.
// rel[n,m] = Q[n] . E_rel[m-n+N-1]

typedef __bf16 bf16x8 __attribute__((ext_vector_type(8)));
typedef __bf16 bf16x4 __attribute__((ext_vector_type(4)));
typedef float  f32x4  __attribute__((ext_vector_type(4)));
typedef float  f32x16 __attribute__((ext_vector_type(16)));

#if __has_builtin(__builtin_amdgcn_exp2f)
#define EXP2(x) __builtin_amdgcn_exp2f(x)
#else
#define EXP2(x) exp2f(x)
#endif

#define QSCALE 0.18033688011f   // (1/8) * log2(e), folded into Q at projection

// async global->LDS, 16B per lane; LDS dest = wave-uniform base + lane*16
#define GLOAD_LDS16(g, l)                                                      \
    __builtin_amdgcn_global_load_lds(                                          \
        (const __attribute__((address_space(1))) unsigned int*)(g),            \
        (__attribute__((address_space(3))) unsigned int*)(l), 16, 0, 0)

// Fragment-stream layouts (per bh, 65536 elems = 128KB):
//  Kf: [t32 = n>>5][ks = d>>4][lane = ((d>>3)&1)*32 + (n&31)][j = d&7]
//  Vf: [t64 = n>>6][ks = (n>>4)&3][dhalf = d>>5][lane = ((n>>3)&1)*32 + (d&31)][j = n&7]
//  Ef: like Kf over 2048 rows (l = row index): [t32 = l>>5][ks][lane][j]

// ---------------- fused fp32 -> bf16 conversion ----------------
__global__ __launch_bounds__(256) void cvt_all(const float* __restrict__ x,
                                               const float* __restrict__ E,
                                               const float* __restrict__ wq,
                                               const float* __restrict__ wk,
                                               const float* __restrict__ wv,
                                               const float* __restrict__ wo,
                                               __bf16* __restrict__ xb,
                                               __bf16* __restrict__ Ef,
                                               __bf16* __restrict__ wqkv,
                                               __bf16* __restrict__ wob) {
    int i = blockIdx.x * 256 + threadIdx.x;
    if (i >= 1081328 ? i < 1343472 : i < 1048576) {
        const float* s; __bf16* d; int off;
        if      (i < 1048576) { s = x;  d = xb;            off = i; }
        else if (i < 1146864) { s = wq; d = wqkv;          off = i - 1081328; }
        else if (i < 1212400) { s = wk; d = wqkv + 262144; off = i - 1146864; }
        else if (i < 1277936) { s = wv; d = wqkv + 524288; off = i - 1212400; }
        else                  { s = wo; d = wob;           off = i - 1277936; }
        float4 v = *(const float4*)(s + (size_t)off * 4);
        bf16x4 o;
        o[0] = (__bf16)v.x; o[1] = (__bf16)v.y; o[2] = (__bf16)v.z; o[3] = (__bf16)v.w;
        *(bf16x4*)(d + (size_t)off * 4) = o;
    } else if (i >= 1048576 && i < 1081328) {
        // E -> fragment stream
        int off = i - 1048576;
        float4 v = *(const float4*)(E + (size_t)off * 4);
        int e0i = off * 4;
        int l = e0i >> 6, d0 = e0i & 63;
        int t32 = l >> 5, cq = l & 31, ks = d0 >> 4, hf = (d0 >> 3) & 1, j = d0 & 7;
        bf16x4 o;
        o[0] = (__bf16)v.x; o[1] = (__bf16)v.y; o[2] = (__bf16)v.z; o[3] = (__bf16)v.w;
        *(bf16x4*)(Ef + ((size_t)((t32 * 4 + ks) * 64) + hf * 32 + cq) * 8 + j) = o;
    }
}

// ---------------- QKV projection GEMM (2-phase pipelined) ----------------
#define QKV_STAGE(BUF, K0)                                                     \
    _Pragma("unroll")                                                          \
    for (int p = 0; p < 4; ++p) {                                              \
        int s = tid + p * 256;                                                 \
        int row = s >> 3, cc = (s & 7) * 8;                                    \
        GLOAD_LDS16(X + (size_t)(m_base + row) * 512 + (K0) + cc,              \
                    &Xs[BUF][0][0] + (size_t)s * 8);                           \
        GLOAD_LDS16(W + (size_t)(j_base + row) * 512 + (K0) + cc,              \
                    &Ws[BUF][0][0] + (size_t)s * 8);                           \
    }

#define QKV_COMPUTE(BUF)                                                       \
    _Pragma("unroll")                                                          \
    for (int kk = 0; kk < 64; kk += 32) {                                      \
        bf16x8 xa[4], wb[4];                                                   \
        _Pragma("unroll")                                                      \
        for (int i = 0; i < 4; ++i)                                            \
            xa[i] = *(const bf16x8*)(&Xs[BUF][wm + i * 16 + col][kk + quad * 8]); \
        _Pragma("unroll")                                                      \
        for (int j = 0; j < 4; ++j)                                            \
            wb[j] = *(const bf16x8*)(&Ws[BUF][wn + j * 16 + col][kk + quad * 8]); \
        if (qk) {                                                              \
            _Pragma("unroll")                                                  \
            for (int i = 0; i < 4; ++i)                                        \
                _Pragma("unroll")                                              \
                for (int j = 0; j < 4; ++j)                                    \
                    acc[i][j] = __builtin_amdgcn_mfma_f32_16x16x32_bf16(wb[i], xa[j], acc[i][j], 0, 0, 0); \
        } else {                                                               \
            _Pragma("unroll")                                                  \
            for (int i = 0; i < 4; ++i)                                        \
                _Pragma("unroll")                                              \
                for (int j = 0; j < 4; ++j)                                    \
                    acc[i][j] = __builtin_amdgcn_mfma_f32_16x16x32_bf16(xa[i], wb[j], acc[i][j], 0, 0, 0); \
        }                                                                      \
    }

__global__ __launch_bounds__(256) void gemm_qkv(const __bf16* __restrict__ X,
                                                const __bf16* __restrict__ W,
                                                __bf16* __restrict__ Qb,
                                                __bf16* __restrict__ Kf,
                                                __bf16* __restrict__ Vf) {
    __shared__ __bf16 Xs[2][128][64];
    __shared__ __bf16 Ws[2][128][64];
    const int tid = threadIdx.x;
    const int wave = tid >> 6, lane = tid & 63;
    const int col = lane & 15, quad = lane >> 4;
    const int m_base = blockIdx.x * 128;
    const int j_base = blockIdx.y * 128;
    const bool qk = (j_base < 1024);
    const int wm = (wave & 1) * 64;
    const int wn = (wave >> 1) * 64;
    const f32x4 fz = {0.f, 0.f, 0.f, 0.f};
    f32x4 acc[4][4];
#pragma unroll
    for (int i = 0; i < 4; ++i)
#pragma unroll
        for (int j = 0; j < 4; ++j) acc[i][j] = fz;

    QKV_STAGE(0, 0)
#pragma unroll 1
    for (int it = 0; it < 7; ++it) {
        const int cur = it & 1;
        if (cur == 0) { QKV_STAGE(1, (it + 1) * 64) } else { QKV_STAGE(0, (it + 1) * 64) }
        // 16 new loads in flight; wait only for the 16 older (current buffer)
        asm volatile("s_waitcnt vmcnt(16)" ::: "memory");
        __builtin_amdgcn_s_barrier();
        if (cur == 0) { QKV_COMPUTE(0) } else { QKV_COMPUTE(1) }
        __builtin_amdgcn_s_barrier();   // protect current buf from next iter's stage
    }
    asm volatile("s_waitcnt vmcnt(0)" ::: "memory");
    __builtin_amdgcn_s_barrier();
    QKV_COMPUTE(1)

    if (qk) {
#pragma unroll
        for (int i = 0; i < 4; ++i) {
#pragma unroll
            for (int j = 0; j < 4; ++j) {
                int jabs = j_base + wn + i * 16 + quad * 4;
                int m = m_base + wm + j * 16 + col;
                int b_ = m >> 10, n = m & 1023;
                int rem = jabs & 511, h = rem >> 6, d = rem & 63;
                bf16x4 v;
                if (jabs < 512) {
                    v[0] = (__bf16)(acc[i][j][0] * QSCALE);
                    v[1] = (__bf16)(acc[i][j][1] * QSCALE);
                    v[2] = (__bf16)(acc[i][j][2] * QSCALE);
                    v[3] = (__bf16)(acc[i][j][3] * QSCALE);
                    *(bf16x4*)(Qb + (((size_t)b_ * 8 + h) * 1024 + n) * 64 + d) = v;
                } else {
                    v[0] = (__bf16)acc[i][j][0]; v[1] = (__bf16)acc[i][j][1];
                    v[2] = (__bf16)acc[i][j][2]; v[3] = (__bf16)acc[i][j][3];
                    int t32 = n >> 5, cq = n & 31, ks = d >> 4, hf = (d >> 3) & 1, jj = d & 7;
                    *(bf16x4*)(Kf + (size_t)(b_ * 8 + h) * 65536 +
                               ((size_t)((t32 * 4 + ks) * 64) + hf * 32 + cq) * 8 + jj) = v;
                }
            }
        }
    } else {
#pragma unroll
        for (int i = 0; i < 4; ++i) {
#pragma unroll
            for (int j = 0; j < 4; ++j) {
                int m = m_base + wm + i * 16 + quad * 4;
                int b_ = m >> 10, n = m & 1023;
                int jabs = j_base + wn + j * 16 + col;
                int rem = jabs & 511, h = rem >> 6, d = rem & 63;
                int t64 = n >> 6, ks = (n >> 4) & 3, hf = (n >> 3) & 1, jj = n & 7;
                int dhalf = d >> 5, cq = d & 31;
                bf16x4 v;
                v[0] = (__bf16)acc[i][j][0]; v[1] = (__bf16)acc[i][j][1];
                v[2] = (__bf16)acc[i][j][2]; v[3] = (__bf16)acc[i][j][3];
                *(bf16x4*)(Vf + (size_t)(b_ * 8 + h) * 65536 +
                           ((size_t)(((t64 * 4 + ks) * 2 + dhalf) * 64) + hf * 32 + cq) * 8 + jj) = v;
            }
        }
    }
}

// ---------------- flash attention (R11-exact: R5 shell + E-carry + load pipeline) ----------------
// grid: x = 16 (64-row n-tiles), y = 64 (b*h). 128 threads = 2 waves, 32 rows each.
#define FLASH_HALF(T, KC0, KC1, KN0, KN1)                                              \
  {                                                                                    \
    const int t_ = (T);                                                                \
    const int teB_ = te0 + 2 * t_ + 1;                                                 \
    bf16x8 e1f[4], e2f[4], v0f[4], v1f[4];                                             \
    _Pragma("unroll")                                                                  \
    for (int ks = 0; ks < 4; ++ks) {                                                   \
      e1f[ks] = *(const bf16x8*)(Ef + ((size_t)((teB_ * 4 + ks) * 64) + lane) * 8);    \
      e2f[ks] = *(const bf16x8*)(Ef + ((size_t)(((teB_ + 1) * 4 + ks) * 64) + lane) * 8); \
    }                                                                                  \
    _Pragma("unroll")                                                                  \
    for (int ks = 0; ks < 4; ++ks) {                                                   \
      v0f[ks] = *(const bf16x8*)(Vfb + ((size_t)(((t_ * 4 + ks) * 2 + 0) * 64) + lane) * 8); \
      v1f[ks] = *(const bf16x8*)(Vfb + ((size_t)(((t_ * 4 + ks) * 2 + 1) * 64) + lane) * 8); \
    }                                                                                  \
    f32x16 qeB = z16, qeC = z16, s0 = z16, s1 = z16;                                   \
    _Pragma("unroll")                                                                  \
    for (int ks = 0; ks < 4; ++ks) {                                                   \
      s0 = __builtin_amdgcn_mfma_f32_32x32x16_bf16(a_q[ks], KC0[ks], s0, 0, 0, 0);     \
      s1 = __builtin_amdgcn_mfma_f32_32x32x16_bf16(a_q[ks], KC1[ks], s1, 0, 0, 0);     \
    }                                                                                  \
    const int t32n_ = (((T) + 1) & 15) * 2;                                            \
    _Pragma("unroll")                                                                  \
    for (int ks = 0; ks < 4; ++ks) {                                                   \
      KN0[ks] = *(const bf16x8*)(Kfb + ((size_t)((t32n_ * 4 + ks) * 64) + lane) * 8);  \
      KN1[ks] = *(const bf16x8*)(Kfb + ((size_t)(((t32n_ + 1) * 4 + ks) * 64) + lane) * 8); \
    }                                                                                  \
    _Pragma("unroll")                                                                  \
    for (int ks = 0; ks < 4; ++ks) {                                                   \
      qeB = __builtin_amdgcn_mfma_f32_32x32x16_bf16(a_q[ks], e1f[ks], qeB, 0, 0, 0);   \
      qeC = __builtin_amdgcn_mfma_f32_32x32x16_bf16(a_q[ks], e2f[ks], qeC, 0, 0, 0);   \
    }                                                                                  \
    _Pragma("unroll")                                                                  \
    for (int r = 0; r < 16; ++r) {                                                     \
      int row = (r & 3) + 8 * (r >> 2) + 4 * half;                                     \
      int tt = colq + 31 - row;                                                        \
      int src = (tt & 31) | (half << 5);                                               \
      float shB = __shfl(qeB[r], src, 64);                                             \
      float shC = __shfl(qeC[r], src, 64);                                             \
      bool sel = (tt >= 32);                                                           \
      float rel0 = sel ? shB : shA[r];                                                 \
      float rel1 = sel ? shC : shB;                                                    \
      float p0 = EXP2(s0[r] + rel0);                                                   \
      float p1 = EXP2(s1[r] + rel1);                                                   \
      rowsum[r] += p0 + p1;                                                            \
      Pw[w][row][colq]      = (__bf16)p0;                                              \
      Pw[w][row][32 + colq] = (__bf16)p1;                                              \
      shA[r] = shC;                                                                    \
    }                                                                                  \
    asm volatile("s_waitcnt lgkmcnt(0)" ::: "memory");                                 \
    _Pragma("unroll")                                                                  \
    for (int ks = 0; ks < 4; ++ks) {                                                   \
      bf16x8 pa = *(const bf16x8*)(&Pw[w][colq][ks * 16 + half * 8]);                  \
      o0 = __builtin_amdgcn_mfma_f32_32x32x16_bf16(pa, v0f[ks], o0, 0, 0, 0);          \
      o1 = __builtin_amdgcn_mfma_f32_32x32x16_bf16(pa, v1f[ks], o1, 0, 0, 0);          \
    }                                                                                  \
    asm volatile("" ::: "memory");                                                     \
  }

__global__ __launch_bounds__(128, 2) void flash_kernel(const __bf16* __restrict__ Qb,
                                                       const __bf16* __restrict__ Kf,
                                                       const __bf16* __restrict__ Vf,
                                                       const __bf16* __restrict__ Ef,
                                                       const float* __restrict__ phase,
                                                       __bf16* __restrict__ Ob) {
    const int bh = blockIdx.y;
    const int n0 = blockIdx.x * 64;
    const int w = threadIdx.x >> 6, lane = threadIdx.x & 63;
    const int colq = lane & 31, half = lane >> 5;
    const int nbase = n0 + w * 32;

    __shared__ __bf16 Pw[2][32][72];   // per-wave P staging; conflict-free

    f32x16 z16;
#pragma unroll
    for (int i = 0; i < 16; ++i) z16[i] = 0.f;

    bf16x8 a_q[4];
#pragma unroll
    for (int ks = 0; ks < 4; ++ks)
        a_q[ks] = *(const bf16x8*)(Qb + ((size_t)bh * 1024 + nbase + colq) * 64 + ks * 16 + half * 8);

    f32x16 o0 = z16, o1 = z16;
    float rowsum[16];
#pragma unroll
    for (int i = 0; i < 16; ++i) rowsum[i] = 0.f;

    const __bf16* Kfb = Kf + (size_t)bh * 65536;
    const __bf16* Vfb = Vf + (size_t)bh * 65536;

    const int te0 = (992 - nbase) >> 5;   // first window tile (>= 0)

    // K double-buffer register sets (t=0 tiles preloaded here)
    bf16x8 kA0[4], kA1[4], kB0[4], kB1[4];
#pragma unroll
    for (int ks = 0; ks < 4; ++ks) {
        kA0[ks] = *(const bf16x8*)(Kfb + ((size_t)((0 * 4 + ks) * 64) + lane) * 8);
        kA1[ks] = *(const bf16x8*)(Kfb + ((size_t)((1 * 4 + ks) * 64) + lane) * 8);
    }

    // prologue: shuffled values of tile te0 (the carried "A" tile)
    float shA[16];
    {
        f32x16 qeA = z16;
#pragma unroll
        for (int ks = 0; ks < 4; ++ks) {
            bf16x8 e = *(const bf16x8*)(Ef + ((size_t)((te0 * 4 + ks) * 64) + lane) * 8);
            qeA = __builtin_amdgcn_mfma_f32_32x32x16_bf16(a_q[ks], e, qeA, 0, 0, 0);
        }
#pragma unroll
        for (int r = 0; r < 16; ++r) {
            int row = (r & 3) + 8 * (r >> 2) + 4 * half;
            int tt = colq + 31 - row;
            int src = (tt & 31) | (half << 5);
            shA[r] = __shfl(qeA[r], src, 64);
        }
    }

#pragma unroll 1
    for (int tt2 = 0; tt2 < 8; ++tt2) {
        FLASH_HALF(2 * tt2,     kA0, kA1, kB0, kB1)
        FLASH_HALF(2 * tt2 + 1, kB0, kB1, kA0, kA1)
    }

    // epilogue: l reduce, scale by phase/l, store via Pw for coalescing
    const int b_ = bh >> 3, hh = bh & 7;
#pragma unroll
    for (int r = 0; r < 16; ++r) {
        float l = rowsum[r];
        l += __shfl_xor(l, 1, 32);
        l += __shfl_xor(l, 2, 32);
        l += __shfl_xor(l, 4, 32);
        l += __shfl_xor(l, 8, 32);
        l += __shfl_xor(l, 16, 32);
        int row = (r & 3) + 8 * (r >> 2) + 4 * half;
        float f = phase[(size_t)bh * 1024 + nbase + row] / l;
        Pw[w][row][colq]      = (__bf16)(o0[r] * f);
        Pw[w][row][32 + colq] = (__bf16)(o1[r] * f);
    }
    asm volatile("s_waitcnt lgkmcnt(0)" ::: "memory");
    {
        int row = lane >> 1, dseg = lane & 1;
        bf16x8 u0 = *(const bf16x8*)(&Pw[w][row][dseg * 32]);
        bf16x8 u1 = *(const bf16x8*)(&Pw[w][row][dseg * 32 + 8]);
        bf16x8 u2 = *(const bf16x8*)(&Pw[w][row][dseg * 32 + 16]);
        bf16x8 u3 = *(const bf16x8*)(&Pw[w][row][dseg * 32 + 24]);
        size_t obase = ((size_t)b_ * 1024 + nbase + row) * 512 + hh * 64 + dseg * 32;
        *(bf16x8*)(Ob + obase)      = u0;
        *(bf16x8*)(Ob + obase + 8)  = u1;
        *(bf16x8*)(Ob + obase + 16) = u2;
        *(bf16x8*)(Ob + obase + 24) = u3;
    }
}

// ---------------- output projection GEMM (2-phase pipelined, 128x64 tiles) ----------------
#define OUT_STAGE(BUF, K0)                                                     \
    _Pragma("unroll")                                                          \
    for (int p = 0; p < 4; ++p) {                                              \
        int s = tid + p * 256;                                                 \
        int row = s >> 3, cc = (s & 7) * 8;                                    \
        GLOAD_LDS16(X + (size_t)(m_base + row) * 512 + (K0) + cc,              \
                    &Xs[BUF][0][0] + (size_t)s * 8);                           \
    }                                                                          \
    _Pragma("unroll")                                                          \
    for (int p = 0; p < 2; ++p) {                                              \
        int s = tid + p * 256;                                                 \
        int row = s >> 3, cc = (s & 7) * 8;                                    \
        GLOAD_LDS16(W + (size_t)(j_base + row) * 512 + (K0) + cc,              \
                    &Ws[BUF][0][0] + (size_t)s * 8);                           \
    }

#define OUT_COMPUTE(BUF)                                                       \
    _Pragma("unroll")                                                          \
    for (int kk = 0; kk < 64; kk += 32) {                                      \
        bf16x8 xa[4], wb[2];                                                   \
        _Pragma("unroll")                                                      \
        for (int j = 0; j < 4; ++j)                                            \
            xa[j] = *(const bf16x8*)(&Xs[BUF][wm + j * 16 + col][kk + quad * 8]); \
        _Pragma("unroll")                                                      \
        for (int i = 0; i < 2; ++i)                                            \
            wb[i] = *(const bf16x8*)(&Ws[BUF][wn + i * 16 + col][kk + quad * 8]); \
        _Pragma("unroll")                                                      \
        for (int i = 0; i < 2; ++i)                                            \
            _Pragma("unroll")                                                  \
            for (int j = 0; j < 4; ++j)                                        \
                acc[i][j] = __builtin_amdgcn_mfma_f32_16x16x32_bf16(wb[i], xa[j], acc[i][j], 0, 0, 0); \
    }

__global__ __launch_bounds__(256) void gemm_out(const __bf16* __restrict__ X,
                                                const __bf16* __restrict__ W,
                                                const float* __restrict__ bo,
                                                float* __restrict__ out) {
    __shared__ __bf16 Xs[2][128][64];
    __shared__ __bf16 Ws[2][64][64];
    const int tid = threadIdx.x;
    const int wave = tid >> 6, lane = tid & 63;
    const int col = lane & 15, quad = lane >> 4;
    const int m_base = blockIdx.x * 128;
    const int j_base = blockIdx.y * 64;
    const int wm = (wave & 1) * 64;
    const int wn = (wave >> 1) * 32;
    const f32x4 fz = {0.f, 0.f, 0.f, 0.f};
    f32x4 acc[2][4];
#pragma unroll
    for (int i = 0; i < 2; ++i)
#pragma unroll
        for (int j = 0; j < 4; ++j) acc[i][j] = fz;

    OUT_STAGE(0, 0)
#pragma unroll 1
    for (int it = 0; it < 7; ++it) {
        const int cur = it & 1;
        if (cur == 0) { OUT_STAGE(1, (it + 1) * 64) } else { OUT_STAGE(0, (it + 1) * 64) }
        // 6 new loads in flight; wait only for the 6 older (current buffer)
        asm volatile("s_waitcnt vmcnt(6)" ::: "memory");
        __builtin_amdgcn_s_barrier();
        if (cur == 0) { OUT_COMPUTE(0) } else { OUT_COMPUTE(1) }
        __builtin_amdgcn_s_barrier();
    }
    asm volatile("s_waitcnt vmcnt(0)" ::: "memory");
    __builtin_amdgcn_s_barrier();
    OUT_COMPUTE(1)

#pragma unroll
    for (int i = 0; i < 2; ++i) {
#pragma unroll
        for (int j = 0; j < 4; ++j) {
            int jabs = j_base + wn + i * 16 + quad * 4;
            int m = m_base + wm + j * 16 + col;
            f32x4 bv = *(const f32x4*)(bo + jabs);
            f32x4 o = acc[i][j] + bv;
            *(f32x4*)(out + (size_t)m * 512 + jabs) = o;
        }
    }
}

extern "C" void kernel_launch(void* const* d_in, const int* in_sizes, int n_in,
                              void* d_out, int out_size, void* d_ws, size_t ws_size,
                              hipStream_t stream) {
    (void)in_sizes; (void)n_in; (void)out_size; (void)ws_size;
    const float* x     = (const float*)d_in[0];
    const float* phase = (const float*)d_in[1];
    const float* E_rel = (const float*)d_in[2];
    const float* W_q   = (const float*)d_in[3];
    const float* W_k   = (const float*)d_in[4];
    const float* W_v   = (const float*)d_in[5];
    const float* W_o   = (const float*)d_in[6];
    const float* b_o   = (const float*)d_in[7];
    float* out = (float*)d_out;

    char* ws = (char*)d_ws;
    __bf16* xb   = (__bf16*)(ws);                 //  8,388,608 B
    __bf16* wqkv = (__bf16*)(ws + 8388608);       //  1,572,864 B
    __bf16* wob  = (__bf16*)(ws + 9961472);       //    524,288 B
    __bf16* Ef   = (__bf16*)(ws + 10485760);      //    262,144 B fragment stream
    __bf16* Qb   = (__bf16*)(ws + 10747904);      //  8,388,608 B (pre-scaled)
    __bf16* Kf   = (__bf16*)(ws + 19136512);      //  8,388,608 B fragment stream
    __bf16* Vf   = (__bf16*)(ws + 27525120);      //  8,388,608 B fragment stream
    __bf16* Ob   = (__bf16*)(ws + 35913728);      //  8,388,608 B

    cvt_all<<<dim3(5249), dim3(256), 0, stream>>>(x, E_rel, W_q, W_k, W_v, W_o,
                                                  xb, Ef, wqkv, wob);
    gemm_qkv<<<dim3(64, 12), dim3(256), 0, stream>>>(xb, wqkv, Qb, Kf, Vf);
    flash_kernel<<<dim3(16, 64), dim3(128), 0, stream>>>(Qb, Kf, Vf, Ef, phase, Ob);
    gemm_out<<<dim3(64, 8), dim3(256), 0, stream>>>(Ob, wob, b_o, out);
}

// Round 7
// 175.870 us; speedup vs baseline: 3.2482x; 1.0315x over previous
//
#include <hip/hip_runtime.h>

// PhaseMultiHeadAttention: B=8, N=1024, D=512, H=8, dh=64
// R17 = R11-exact flash (proven 55.7us) + BK=32 2-phase GEMMs:
//   R16 lesson: 2-phase at BK=64 doubled LDS (qkv 32->64KB), cut 3->2
//   blocks/CU -> +10us. This version halves the K-step so the double
//   buffer fits in R11's LDS footprint (qkv 32KB, out 24KB): occupancy
//   identical to R11, pure overlap added. Counted waits now correct:
//   qkv 4 loads/stage -> vmcnt(4); out 3 loads/stage -> vmcnt(3);
//   vmcnt(0) only before the final tile. Side bonus: 64B LDS row stride
//   halves the ds_read bank conflict (16-way -> 8-way).
// rel[n,m] = Q[n] . E_rel[m-n+N-1]

typedef __bf16 bf16x8 __attribute__((ext_vector_type(8)));
typedef __bf16 bf16x4 __attribute__((ext_vector_type(4)));
typedef float  f32x4  __attribute__((ext_vector_type(4)));
typedef float  f32x16 __attribute__((ext_vector_type(16)));

#if __has_builtin(__builtin_amdgcn_exp2f)
#define EXP2(x) __builtin_amdgcn_exp2f(x)
#else
#define EXP2(x) exp2f(x)
#endif

#define QSCALE 0.18033688011f   // (1/8) * log2(e), folded into Q at projection

// async global->LDS, 16B per lane; LDS dest = wave-uniform base + lane*16
#define GLOAD_LDS16(g, l)                                                      \
    __builtin_amdgcn_global_load_lds(                                          \
        (const __attribute__((address_space(1))) unsigned int*)(g),            \
        (__attribute__((address_space(3))) unsigned int*)(l), 16, 0, 0)

// Fragment-stream layouts (per bh, 65536 elems = 128KB):
//  Kf: [t32 = n>>5][ks = d>>4][lane = ((d>>3)&1)*32 + (n&31)][j = d&7]
//  Vf: [t64 = n>>6][ks = (n>>4)&3][dhalf = d>>5][lane = ((n>>3)&1)*32 + (d&31)][j = n&7]
//  Ef: like Kf over 2048 rows (l = row index): [t32 = l>>5][ks][lane][j]

// ---------------- fused fp32 -> bf16 conversion ----------------
__global__ __launch_bounds__(256) void cvt_all(const float* __restrict__ x,
                                               const float* __restrict__ E,
                                               const float* __restrict__ wq,
                                               const float* __restrict__ wk,
                                               const float* __restrict__ wv,
                                               const float* __restrict__ wo,
                                               __bf16* __restrict__ xb,
                                               __bf16* __restrict__ Ef,
                                               __bf16* __restrict__ wqkv,
                                               __bf16* __restrict__ wob) {
    int i = blockIdx.x * 256 + threadIdx.x;
    if (i >= 1081328 ? i < 1343472 : i < 1048576) {
        const float* s; __bf16* d; int off;
        if      (i < 1048576) { s = x;  d = xb;            off = i; }
        else if (i < 1146864) { s = wq; d = wqkv;          off = i - 1081328; }
        else if (i < 1212400) { s = wk; d = wqkv + 262144; off = i - 1146864; }
        else if (i < 1277936) { s = wv; d = wqkv + 524288; off = i - 1212400; }
        else                  { s = wo; d = wob;           off = i - 1277936; }
        float4 v = *(const float4*)(s + (size_t)off * 4);
        bf16x4 o;
        o[0] = (__bf16)v.x; o[1] = (__bf16)v.y; o[2] = (__bf16)v.z; o[3] = (__bf16)v.w;
        *(bf16x4*)(d + (size_t)off * 4) = o;
    } else if (i >= 1048576 && i < 1081328) {
        // E -> fragment stream
        int off = i - 1048576;
        float4 v = *(const float4*)(E + (size_t)off * 4);
        int e0i = off * 4;
        int l = e0i >> 6, d0 = e0i & 63;
        int t32 = l >> 5, cq = l & 31, ks = d0 >> 4, hf = (d0 >> 3) & 1, j = d0 & 7;
        bf16x4 o;
        o[0] = (__bf16)v.x; o[1] = (__bf16)v.y; o[2] = (__bf16)v.z; o[3] = (__bf16)v.w;
        *(bf16x4*)(Ef + ((size_t)((t32 * 4 + ks) * 64) + hf * 32 + cq) * 8 + j) = o;
    }
}

// ---------------- QKV projection GEMM (BK=32, 2-phase) ----------------
#define QKV_STAGE(BUF, K0)                                                     \
    _Pragma("unroll")                                                          \
    for (int p = 0; p < 2; ++p) {                                              \
        int s = tid + p * 256;                                                 \
        int row = s >> 2, cc = (s & 3) * 8;                                    \
        GLOAD_LDS16(X + (size_t)(m_base + row) * 512 + (K0) + cc,              \
                    &Xs[BUF][0][0] + (size_t)s * 8);                           \
        GLOAD_LDS16(W + (size_t)(j_base + row) * 512 + (K0) + cc,              \
                    &Ws[BUF][0][0] + (size_t)s * 8);                           \
    }

#define QKV_COMPUTE(BUF)                                                       \
    {                                                                          \
        bf16x8 xa[4], wb[4];                                                   \
        _Pragma("unroll")                                                      \
        for (int i = 0; i < 4; ++i)                                            \
            xa[i] = *(const bf16x8*)(&Xs[BUF][wm + i * 16 + col][quad * 8]);   \
        _Pragma("unroll")                                                      \
        for (int j = 0; j < 4; ++j)                                            \
            wb[j] = *(const bf16x8*)(&Ws[BUF][wn + j * 16 + col][quad * 8]);   \
        if (qk) {                                                              \
            _Pragma("unroll")                                                  \
            for (int i = 0; i < 4; ++i)                                        \
                _Pragma("unroll")                                              \
                for (int j = 0; j < 4; ++j)                                    \
                    acc[i][j] = __builtin_amdgcn_mfma_f32_16x16x32_bf16(wb[i], xa[j], acc[i][j], 0, 0, 0); \
        } else {                                                               \
            _Pragma("unroll")                                                  \
            for (int i = 0; i < 4; ++i)                                        \
                _Pragma("unroll")                                              \
                for (int j = 0; j < 4; ++j)                                    \
                    acc[i][j] = __builtin_amdgcn_mfma_f32_16x16x32_bf16(xa[i], wb[j], acc[i][j], 0, 0, 0); \
        }                                                                      \
    }

__global__ __launch_bounds__(256) void gemm_qkv(const __bf16* __restrict__ X,
                                                const __bf16* __restrict__ W,
                                                __bf16* __restrict__ Qb,
                                                __bf16* __restrict__ Kf,
                                                __bf16* __restrict__ Vf) {
    __shared__ __bf16 Xs[2][128][32];   // 16 KB
    __shared__ __bf16 Ws[2][128][32];   // 16 KB  (total 32 KB = R11 footprint)
    const int tid = threadIdx.x;
    const int wave = tid >> 6, lane = tid & 63;
    const int col = lane & 15, quad = lane >> 4;
    const int m_base = blockIdx.x * 128;
    const int j_base = blockIdx.y * 128;
    const bool qk = (j_base < 1024);
    const int wm = (wave & 1) * 64;
    const int wn = (wave >> 1) * 64;
    const f32x4 fz = {0.f, 0.f, 0.f, 0.f};
    f32x4 acc[4][4];
#pragma unroll
    for (int i = 0; i < 4; ++i)
#pragma unroll
        for (int j = 0; j < 4; ++j) acc[i][j] = fz;

    QKV_STAGE(0, 0)
#pragma unroll 1
    for (int it = 0; it < 15; ++it) {
        if ((it & 1) == 0) { QKV_STAGE(1, (it + 1) * 32) } else { QKV_STAGE(0, (it + 1) * 32) }
        // 8 outstanding; wait for the 4 older (current buffer) only
        asm volatile("s_waitcnt vmcnt(4)" ::: "memory");
        __builtin_amdgcn_s_barrier();
        if ((it & 1) == 0) { QKV_COMPUTE(0) } else { QKV_COMPUTE(1) }
        __builtin_amdgcn_s_barrier();   // protect buf from next iter's stage
    }
    asm volatile("s_waitcnt vmcnt(0)" ::: "memory");
    __builtin_amdgcn_s_barrier();
    QKV_COMPUTE(1)

    if (qk) {
#pragma unroll
        for (int i = 0; i < 4; ++i) {
#pragma unroll
            for (int j = 0; j < 4; ++j) {
                int jabs = j_base + wn + i * 16 + quad * 4;
                int m = m_base + wm + j * 16 + col;
                int b_ = m >> 10, n = m & 1023;
                int rem = jabs & 511, h = rem >> 6, d = rem & 63;
                bf16x4 v;
                if (jabs < 512) {
                    v[0] = (__bf16)(acc[i][j][0] * QSCALE);
                    v[1] = (__bf16)(acc[i][j][1] * QSCALE);
                    v[2] = (__bf16)(acc[i][j][2] * QSCALE);
                    v[3] = (__bf16)(acc[i][j][3] * QSCALE);
                    *(bf16x4*)(Qb + (((size_t)b_ * 8 + h) * 1024 + n) * 64 + d) = v;
                } else {
                    v[0] = (__bf16)acc[i][j][0]; v[1] = (__bf16)acc[i][j][1];
                    v[2] = (__bf16)acc[i][j][2]; v[3] = (__bf16)acc[i][j][3];
                    int t32 = n >> 5, cq = n & 31, ks = d >> 4, hf = (d >> 3) & 1, jj = d & 7;
                    *(bf16x4*)(Kf + (size_t)(b_ * 8 + h) * 65536 +
                               ((size_t)((t32 * 4 + ks) * 64) + hf * 32 + cq) * 8 + jj) = v;
                }
            }
        }
    } else {
#pragma unroll
        for (int i = 0; i < 4; ++i) {
#pragma unroll
            for (int j = 0; j < 4; ++j) {
                int m = m_base + wm + i * 16 + quad * 4;
                int b_ = m >> 10, n = m & 1023;
                int jabs = j_base + wn + j * 16 + col;
                int rem = jabs & 511, h = rem >> 6, d = rem & 63;
                int t64 = n >> 6, ks = (n >> 4) & 3, hf = (n >> 3) & 1, jj = n & 7;
                int dhalf = d >> 5, cq = d & 31;
                bf16x4 v;
                v[0] = (__bf16)acc[i][j][0]; v[1] = (__bf16)acc[i][j][1];
                v[2] = (__bf16)acc[i][j][2]; v[3] = (__bf16)acc[i][j][3];
                *(bf16x4*)(Vf + (size_t)(b_ * 8 + h) * 65536 +
                           ((size_t)(((t64 * 4 + ks) * 2 + dhalf) * 64) + hf * 32 + cq) * 8 + jj) = v;
            }
        }
    }
}

// ---------------- flash attention (R11-exact: R5 shell + E-carry + load pipeline) ----------------
// grid: x = 16 (64-row n-tiles), y = 64 (b*h). 128 threads = 2 waves, 32 rows each.
#define FLASH_HALF(T, KC0, KC1, KN0, KN1)                                              \
  {                                                                                    \
    const int t_ = (T);                                                                \
    const int teB_ = te0 + 2 * t_ + 1;                                                 \
    bf16x8 e1f[4], e2f[4], v0f[4], v1f[4];                                             \
    _Pragma("unroll")                                                                  \
    for (int ks = 0; ks < 4; ++ks) {                                                   \
      e1f[ks] = *(const bf16x8*)(Ef + ((size_t)((teB_ * 4 + ks) * 64) + lane) * 8);    \
      e2f[ks] = *(const bf16x8*)(Ef + ((size_t)(((teB_ + 1) * 4 + ks) * 64) + lane) * 8); \
    }                                                                                  \
    _Pragma("unroll")                                                                  \
    for (int ks = 0; ks < 4; ++ks) {                                                   \
      v0f[ks] = *(const bf16x8*)(Vfb + ((size_t)(((t_ * 4 + ks) * 2 + 0) * 64) + lane) * 8); \
      v1f[ks] = *(const bf16x8*)(Vfb + ((size_t)(((t_ * 4 + ks) * 2 + 1) * 64) + lane) * 8); \
    }                                                                                  \
    f32x16 qeB = z16, qeC = z16, s0 = z16, s1 = z16;                                   \
    _Pragma("unroll")                                                                  \
    for (int ks = 0; ks < 4; ++ks) {                                                   \
      s0 = __builtin_amdgcn_mfma_f32_32x32x16_bf16(a_q[ks], KC0[ks], s0, 0, 0, 0);     \
      s1 = __builtin_amdgcn_mfma_f32_32x32x16_bf16(a_q[ks], KC1[ks], s1, 0, 0, 0);     \
    }                                                                                  \
    const int t32n_ = (((T) + 1) & 15) * 2;                                            \
    _Pragma("unroll")                                                                  \
    for (int ks = 0; ks < 4; ++ks) {                                                   \
      KN0[ks] = *(const bf16x8*)(Kfb + ((size_t)((t32n_ * 4 + ks) * 64) + lane) * 8);  \
      KN1[ks] = *(const bf16x8*)(Kfb + ((size_t)(((t32n_ + 1) * 4 + ks) * 64) + lane) * 8); \
    }                                                                                  \
    _Pragma("unroll")                                                                  \
    for (int ks = 0; ks < 4; ++ks) {                                                   \
      qeB = __builtin_amdgcn_mfma_f32_32x32x16_bf16(a_q[ks], e1f[ks], qeB, 0, 0, 0);   \
      qeC = __builtin_amdgcn_mfma_f32_32x32x16_bf16(a_q[ks], e2f[ks], qeC, 0, 0, 0);   \
    }                                                                                  \
    _Pragma("unroll")                                                                  \
    for (int r = 0; r < 16; ++r) {                                                     \
      int row = (r & 3) + 8 * (r >> 2) + 4 * half;                                     \
      int tt = colq + 31 - row;                                                        \
      int src = (tt & 31) | (half << 5);                                               \
      float shB = __shfl(qeB[r], src, 64);                                             \
      float shC = __shfl(qeC[r], src, 64);                                             \
      bool sel = (tt >= 32);                                                           \
      float rel0 = sel ? shB : shA[r];                                                 \
      float rel1 = sel ? shC : shB;                                                    \
      float p0 = EXP2(s0[r] + rel0);                                                   \
      float p1 = EXP2(s1[r] + rel1);                                                   \
      rowsum[r] += p0 + p1;                                                            \
      Pw[w][row][colq]      = (__bf16)p0;                                              \
      Pw[w][row][32 + colq] = (__bf16)p1;                                              \
      shA[r] = shC;                                                                    \
    }                                                                                  \
    asm volatile("s_waitcnt lgkmcnt(0)" ::: "memory");                                 \
    _Pragma("unroll")                                                                  \
    for (int ks = 0; ks < 4; ++ks) {                                                   \
      bf16x8 pa = *(const bf16x8*)(&Pw[w][colq][ks * 16 + half * 8]);                  \
      o0 = __builtin_amdgcn_mfma_f32_32x32x16_bf16(pa, v0f[ks], o0, 0, 0, 0);          \
      o1 = __builtin_amdgcn_mfma_f32_32x32x16_bf16(pa, v1f[ks], o1, 0, 0, 0);          \
    }                                                                                  \
    asm volatile("" ::: "memory");                                                     \
  }

__global__ __launch_bounds__(128, 2) void flash_kernel(const __bf16* __restrict__ Qb,
                                                       const __bf16* __restrict__ Kf,
                                                       const __bf16* __restrict__ Vf,
                                                       const __bf16* __restrict__ Ef,
                                                       const float* __restrict__ phase,
                                                       __bf16* __restrict__ Ob) {
    const int bh = blockIdx.y;
    const int n0 = blockIdx.x * 64;
    const int w = threadIdx.x >> 6, lane = threadIdx.x & 63;
    const int colq = lane & 31, half = lane >> 5;
    const int nbase = n0 + w * 32;

    __shared__ __bf16 Pw[2][32][72];   // per-wave P staging; conflict-free

    f32x16 z16;
#pragma unroll
    for (int i = 0; i < 16; ++i) z16[i] = 0.f;

    bf16x8 a_q[4];
#pragma unroll
    for (int ks = 0; ks < 4; ++ks)
        a_q[ks] = *(const bf16x8*)(Qb + ((size_t)bh * 1024 + nbase + colq) * 64 + ks * 16 + half * 8);

    f32x16 o0 = z16, o1 = z16;
    float rowsum[16];
#pragma unroll
    for (int i = 0; i < 16; ++i) rowsum[i] = 0.f;

    const __bf16* Kfb = Kf + (size_t)bh * 65536;
    const __bf16* Vfb = Vf + (size_t)bh * 65536;

    const int te0 = (992 - nbase) >> 5;   // first window tile (>= 0)

    // K double-buffer register sets (t=0 tiles preloaded here)
    bf16x8 kA0[4], kA1[4], kB0[4], kB1[4];
#pragma unroll
    for (int ks = 0; ks < 4; ++ks) {
        kA0[ks] = *(const bf16x8*)(Kfb + ((size_t)((0 * 4 + ks) * 64) + lane) * 8);
        kA1[ks] = *(const bf16x8*)(Kfb + ((size_t)((1 * 4 + ks) * 64) + lane) * 8);
    }

    // prologue: shuffled values of tile te0 (the carried "A" tile)
    float shA[16];
    {
        f32x16 qeA = z16;
#pragma unroll
        for (int ks = 0; ks < 4; ++ks) {
            bf16x8 e = *(const bf16x8*)(Ef + ((size_t)((te0 * 4 + ks) * 64) + lane) * 8);
            qeA = __builtin_amdgcn_mfma_f32_32x32x16_bf16(a_q[ks], e, qeA, 0, 0, 0);
        }
#pragma unroll
        for (int r = 0; r < 16; ++r) {
            int row = (r & 3) + 8 * (r >> 2) + 4 * half;
            int tt = colq + 31 - row;
            int src = (tt & 31) | (half << 5);
            shA[r] = __shfl(qeA[r], src, 64);
        }
    }

#pragma unroll 1
    for (int tt2 = 0; tt2 < 8; ++tt2) {
        FLASH_HALF(2 * tt2,     kA0, kA1, kB0, kB1)
        FLASH_HALF(2 * tt2 + 1, kB0, kB1, kA0, kA1)
    }

    // epilogue: l reduce, scale by phase/l, store via Pw for coalescing
    const int b_ = bh >> 3, hh = bh & 7;
#pragma unroll
    for (int r = 0; r < 16; ++r) {
        float l = rowsum[r];
        l += __shfl_xor(l, 1, 32);
        l += __shfl_xor(l, 2, 32);
        l += __shfl_xor(l, 4, 32);
        l += __shfl_xor(l, 8, 32);
        l += __shfl_xor(l, 16, 32);
        int row = (r & 3) + 8 * (r >> 2) + 4 * half;
        float f = phase[(size_t)bh * 1024 + nbase + row] / l;
        Pw[w][row][colq]      = (__bf16)(o0[r] * f);
        Pw[w][row][32 + colq] = (__bf16)(o1[r] * f);
    }
    asm volatile("s_waitcnt lgkmcnt(0)" ::: "memory");
    {
        int row = lane >> 1, dseg = lane & 1;
        bf16x8 u0 = *(const bf16x8*)(&Pw[w][row][dseg * 32]);
        bf16x8 u1 = *(const bf16x8*)(&Pw[w][row][dseg * 32 + 8]);
        bf16x8 u2 = *(const bf16x8*)(&Pw[w][row][dseg * 32 + 16]);
        bf16x8 u3 = *(const bf16x8*)(&Pw[w][row][dseg * 32 + 24]);
        size_t obase = ((size_t)b_ * 1024 + nbase + row) * 512 + hh * 64 + dseg * 32;
        *(bf16x8*)(Ob + obase)      = u0;
        *(bf16x8*)(Ob + obase + 8)  = u1;
        *(bf16x8*)(Ob + obase + 16) = u2;
        *(bf16x8*)(Ob + obase + 24) = u3;
    }
}

// ---------------- output projection GEMM (BK=32, 2-phase, 128x64 tiles) ----------------
#define OUT_STAGE(BUF, K0)                                                     \
    _Pragma("unroll")                                                          \
    for (int p = 0; p < 2; ++p) {                                              \
        int s = tid + p * 256;                                                 \
        int row = s >> 2, cc = (s & 3) * 8;                                    \
        GLOAD_LDS16(X + (size_t)(m_base + row) * 512 + (K0) + cc,              \
                    &Xs[BUF][0][0] + (size_t)s * 8);                           \
    }                                                                          \
    {                                                                          \
        int row = tid >> 2, cc = (tid & 3) * 8;                                \
        GLOAD_LDS16(W + (size_t)(j_base + row) * 512 + (K0) + cc,              \
                    &Ws[BUF][0][0] + (size_t)tid * 8);                         \
    }

#define OUT_COMPUTE(BUF)                                                       \
    {                                                                          \
        bf16x8 xa[4], wb[2];                                                   \
        _Pragma("unroll")                                                      \
        for (int j = 0; j < 4; ++j)                                            \
            xa[j] = *(const bf16x8*)(&Xs[BUF][wm + j * 16 + col][quad * 8]);   \
        _Pragma("unroll")                                                      \
        for (int i = 0; i < 2; ++i)                                            \
            wb[i] = *(const bf16x8*)(&Ws[BUF][wn + i * 16 + col][quad * 8]);   \
        _Pragma("unroll")                                                      \
        for (int i = 0; i < 2; ++i)                                            \
            _Pragma("unroll")                                                  \
            for (int j = 0; j < 4; ++j)                                        \
                acc[i][j] = __builtin_amdgcn_mfma_f32_16x16x32_bf16(wb[i], xa[j], acc[i][j], 0, 0, 0); \
    }

__global__ __launch_bounds__(256) void gemm_out(const __bf16* __restrict__ X,
                                                const __bf16* __restrict__ W,
                                                const float* __restrict__ bo,
                                                float* __restrict__ out) {
    __shared__ __bf16 Xs[2][128][32];   // 16 KB
    __shared__ __bf16 Ws[2][64][32];    //  8 KB  (total 24 KB = R11 footprint)
    const int tid = threadIdx.x;
    const int wave = tid >> 6, lane = tid & 63;
    const int col = lane & 15, quad = lane >> 4;
    const int m_base = blockIdx.x * 128;
    const int j_base = blockIdx.y * 64;
    const int wm = (wave & 1) * 64;
    const int wn = (wave >> 1) * 32;
    const f32x4 fz = {0.f, 0.f, 0.f, 0.f};
    f32x4 acc[2][4];
#pragma unroll
    for (int i = 0; i < 2; ++i)
#pragma unroll
        for (int j = 0; j < 4; ++j) acc[i][j] = fz;

    OUT_STAGE(0, 0)
#pragma unroll 1
    for (int it = 0; it < 15; ++it) {
        if ((it & 1) == 0) { OUT_STAGE(1, (it + 1) * 32) } else { OUT_STAGE(0, (it + 1) * 32) }
        // 6 outstanding; wait for the 3 older (current buffer) only
        asm volatile("s_waitcnt vmcnt(3)" ::: "memory");
        __builtin_amdgcn_s_barrier();
        if ((it & 1) == 0) { OUT_COMPUTE(0) } else { OUT_COMPUTE(1) }
        __builtin_amdgcn_s_barrier();
    }
    asm volatile("s_waitcnt vmcnt(0)" ::: "memory");
    __builtin_amdgcn_s_barrier();
    OUT_COMPUTE(1)

#pragma unroll
    for (int i = 0; i < 2; ++i) {
#pragma unroll
        for (int j = 0; j < 4; ++j) {
            int jabs = j_base + wn + i * 16 + quad * 4;
            int m = m_base + wm + j * 16 + col;
            f32x4 bv = *(const f32x4*)(bo + jabs);
            f32x4 o = acc[i][j] + bv;
            *(f32x4*)(out + (size_t)m * 512 + jabs) = o;
        }
    }
}

extern "C" void kernel_launch(void* const* d_in, const int* in_sizes, int n_in,
                              void* d_out, int out_size, void* d_ws, size_t ws_size,
                              hipStream_t stream) {
    (void)in_sizes; (void)n_in; (void)out_size; (void)ws_size;
    const float* x     = (const float*)d_in[0];
    const float* phase = (const float*)d_in[1];
    const float* E_rel = (const float*)d_in[2];
    const float* W_q   = (const float*)d_in[3];
    const float* W_k   = (const float*)d_in[4];
    const float* W_v   = (const float*)d_in[5];
    const float* W_o   = (const float*)d_in[6];
    const float* b_o   = (const float*)d_in[7];
    float* out = (float*)d_out;

    char* ws = (char*)d_ws;
    __bf16* xb   = (__bf16*)(ws);                 //  8,388,608 B
    __bf16* wqkv = (__bf16*)(ws + 8388608);       //  1,572,864 B
    __bf16* wob  = (__bf16*)(ws + 9961472);       //    524,288 B
    __bf16* Ef   = (__bf16*)(ws + 10485760);      //    262,144 B fragment stream
    __bf16* Qb   = (__bf16*)(ws + 10747904);      //  8,388,608 B (pre-scaled)
    __bf16* Kf   = (__bf16*)(ws + 19136512);      //  8,388,608 B fragment stream
    __bf16* Vf   = (__bf16*)(ws + 27525120);      //  8,388,608 B fragment stream
    __bf16* Ob   = (__bf16*)(ws + 35913728);      //  8,388,608 B

    cvt_all<<<dim3(5249), dim3(256), 0, stream>>>(x, E_rel, W_q, W_k, W_v, W_o,
                                                  xb, Ef, wqkv, wob);
    gemm_qkv<<<dim3(64, 12), dim3(256), 0, stream>>>(xb, wqkv, Qb, Kf, Vf);
    flash_kernel<<<dim3(16, 64), dim3(128), 0, stream>>>(Qb, Kf, Vf, Ef, phase, Ob);
    gemm_out<<<dim3(64, 8), dim3(256), 0, stream>>>(Ob, wob, b_o, out);
}

// Round 8
// 171.232 us; speedup vs baseline: 3.3361x; 1.0271x over previous
//
#include <hip/hip_runtime.h>

// PhaseMultiHeadAttention: B=8, N=1024, D=512, H=8, dh=64
// R18 = R11-exact GEMMs (2-phase experiments at BK=64/BK=32 both regressed:
// occupancy loss resp. barrier overhead -- reverted per pre-commitment) +
// two flash micro-fixes, keeping the R11 shell bit-identical in math:
//  (1) fold zero-init into the first MFMA of each accumulator
//      (s0 = mfma(a,k,z16) explicitly) -- removes ~64 accvgpr zero-movs
//      per half-iteration that showed up as inflated VALUBusy.
//  (2) double-buffer the per-wave P staging LDS (Pw[2][...]) and drop the
//      trailing memory clobber: the WAR hazard it guarded is gone, so the
//      compiler may schedule the NEXT half's E/V/K global loads into the
//      PV MFMA chain's stall shadow (in-order issue was blocking them).
// rel[n,m] = Q[n] . E_rel[m-n+N-1]

typedef __bf16 bf16x8 __attribute__((ext_vector_type(8)));
typedef __bf16 bf16x4 __attribute__((ext_vector_type(4)));
typedef float  f32x4  __attribute__((ext_vector_type(4)));
typedef float  f32x16 __attribute__((ext_vector_type(16)));

#if __has_builtin(__builtin_amdgcn_exp2f)
#define EXP2(x) __builtin_amdgcn_exp2f(x)
#else
#define EXP2(x) exp2f(x)
#endif

#define QSCALE 0.18033688011f   // (1/8) * log2(e), folded into Q at projection

// async global->LDS, 16B per lane; LDS dest = wave-uniform base + lane*16
#define GLOAD_LDS16(g, l)                                                      \
    __builtin_amdgcn_global_load_lds(                                          \
        (const __attribute__((address_space(1))) unsigned int*)(g),            \
        (__attribute__((address_space(3))) unsigned int*)(l), 16, 0, 0)

// Fragment-stream layouts (per bh, 65536 elems = 128KB):
//  Kf: [t32 = n>>5][ks = d>>4][lane = ((d>>3)&1)*32 + (n&31)][j = d&7]
//  Vf: [t64 = n>>6][ks = (n>>4)&3][dhalf = d>>5][lane = ((n>>3)&1)*32 + (d&31)][j = n&7]
//  Ef: like Kf over 2048 rows (l = row index): [t32 = l>>5][ks][lane][j]

// ---------------- fused fp32 -> bf16 conversion ----------------
__global__ __launch_bounds__(256) void cvt_all(const float* __restrict__ x,
                                               const float* __restrict__ E,
                                               const float* __restrict__ wq,
                                               const float* __restrict__ wk,
                                               const float* __restrict__ wv,
                                               const float* __restrict__ wo,
                                               __bf16* __restrict__ xb,
                                               __bf16* __restrict__ Ef,
                                               __bf16* __restrict__ wqkv,
                                               __bf16* __restrict__ wob) {
    int i = blockIdx.x * 256 + threadIdx.x;
    if (i >= 1081328 ? i < 1343472 : i < 1048576) {
        const float* s; __bf16* d; int off;
        if      (i < 1048576) { s = x;  d = xb;            off = i; }
        else if (i < 1146864) { s = wq; d = wqkv;          off = i - 1081328; }
        else if (i < 1212400) { s = wk; d = wqkv + 262144; off = i - 1146864; }
        else if (i < 1277936) { s = wv; d = wqkv + 524288; off = i - 1212400; }
        else                  { s = wo; d = wob;           off = i - 1277936; }
        float4 v = *(const float4*)(s + (size_t)off * 4);
        bf16x4 o;
        o[0] = (__bf16)v.x; o[1] = (__bf16)v.y; o[2] = (__bf16)v.z; o[3] = (__bf16)v.w;
        *(bf16x4*)(d + (size_t)off * 4) = o;
    } else if (i >= 1048576 && i < 1081328) {
        // E -> fragment stream
        int off = i - 1048576;
        float4 v = *(const float4*)(E + (size_t)off * 4);
        int e0i = off * 4;
        int l = e0i >> 6, d0 = e0i & 63;
        int t32 = l >> 5, cq = l & 31, ks = d0 >> 4, hf = (d0 >> 3) & 1, j = d0 & 7;
        bf16x4 o;
        o[0] = (__bf16)v.x; o[1] = (__bf16)v.y; o[2] = (__bf16)v.z; o[3] = (__bf16)v.w;
        *(bf16x4*)(Ef + ((size_t)((t32 * 4 + ks) * 64) + hf * 32 + cq) * 8 + j) = o;
    }
}

// ---------------- QKV projection GEMM (R11-exact) ----------------
__global__ __launch_bounds__(256) void gemm_qkv(const __bf16* __restrict__ X,
                                                const __bf16* __restrict__ W,
                                                __bf16* __restrict__ Qb,
                                                __bf16* __restrict__ Kf,
                                                __bf16* __restrict__ Vf) {
    __shared__ __bf16 Xs[128][64];
    __shared__ __bf16 Ws[128][64];
    const int tid = threadIdx.x;
    const int wave = tid >> 6, lane = tid & 63;
    const int col = lane & 15, quad = lane >> 4;
    const int m_base = blockIdx.x * 128;
    const int j_base = blockIdx.y * 128;
    const bool qk = (j_base < 1024);
    const int wm = (wave & 1) * 64;
    const int wn = (wave >> 1) * 64;
    const f32x4 fz = {0.f, 0.f, 0.f, 0.f};
    f32x4 acc[4][4];
#pragma unroll
    for (int i = 0; i < 4; ++i)
#pragma unroll
        for (int j = 0; j < 4; ++j) acc[i][j] = fz;

    for (int k0 = 0; k0 < 512; k0 += 64) {
#pragma unroll
        for (int p = 0; p < 4; ++p) {
            int s = tid + p * 256;
            int row = s >> 3, cc = (s & 7) * 8;
            GLOAD_LDS16(X + (size_t)(m_base + row) * 512 + k0 + cc, &Xs[0][0] + (size_t)s * 8);
            GLOAD_LDS16(W + (size_t)(j_base + row) * 512 + k0 + cc, &Ws[0][0] + (size_t)s * 8);
        }
        __syncthreads();
#pragma unroll
        for (int kk = 0; kk < 64; kk += 32) {
            bf16x8 xa[4], wb[4];
#pragma unroll
            for (int i = 0; i < 4; ++i) xa[i] = *(const bf16x8*)(&Xs[wm + i * 16 + col][kk + quad * 8]);
#pragma unroll
            for (int j = 0; j < 4; ++j) wb[j] = *(const bf16x8*)(&Ws[wn + j * 16 + col][kk + quad * 8]);
            if (qk) {
#pragma unroll
                for (int i = 0; i < 4; ++i)
#pragma unroll
                    for (int j = 0; j < 4; ++j)
                        acc[i][j] = __builtin_amdgcn_mfma_f32_16x16x32_bf16(wb[i], xa[j], acc[i][j], 0, 0, 0);
            } else {
#pragma unroll
                for (int i = 0; i < 4; ++i)
#pragma unroll
                    for (int j = 0; j < 4; ++j)
                        acc[i][j] = __builtin_amdgcn_mfma_f32_16x16x32_bf16(xa[i], wb[j], acc[i][j], 0, 0, 0);
            }
        }
        __syncthreads();
    }
    if (qk) {
#pragma unroll
        for (int i = 0; i < 4; ++i) {
#pragma unroll
            for (int j = 0; j < 4; ++j) {
                int jabs = j_base + wn + i * 16 + quad * 4;
                int m = m_base + wm + j * 16 + col;
                int b_ = m >> 10, n = m & 1023;
                int rem = jabs & 511, h = rem >> 6, d = rem & 63;
                bf16x4 v;
                if (jabs < 512) {
                    v[0] = (__bf16)(acc[i][j][0] * QSCALE);
                    v[1] = (__bf16)(acc[i][j][1] * QSCALE);
                    v[2] = (__bf16)(acc[i][j][2] * QSCALE);
                    v[3] = (__bf16)(acc[i][j][3] * QSCALE);
                    *(bf16x4*)(Qb + (((size_t)b_ * 8 + h) * 1024 + n) * 64 + d) = v;
                } else {
                    v[0] = (__bf16)acc[i][j][0]; v[1] = (__bf16)acc[i][j][1];
                    v[2] = (__bf16)acc[i][j][2]; v[3] = (__bf16)acc[i][j][3];
                    int t32 = n >> 5, cq = n & 31, ks = d >> 4, hf = (d >> 3) & 1, jj = d & 7;
                    *(bf16x4*)(Kf + (size_t)(b_ * 8 + h) * 65536 +
                               ((size_t)((t32 * 4 + ks) * 64) + hf * 32 + cq) * 8 + jj) = v;
                }
            }
        }
    } else {
#pragma unroll
        for (int i = 0; i < 4; ++i) {
#pragma unroll
            for (int j = 0; j < 4; ++j) {
                int m = m_base + wm + i * 16 + quad * 4;
                int b_ = m >> 10, n = m & 1023;
                int jabs = j_base + wn + j * 16 + col;
                int rem = jabs & 511, h = rem >> 6, d = rem & 63;
                int t64 = n >> 6, ks = (n >> 4) & 3, hf = (n >> 3) & 1, jj = n & 7;
                int dhalf = d >> 5, cq = d & 31;
                bf16x4 v;
                v[0] = (__bf16)acc[i][j][0]; v[1] = (__bf16)acc[i][j][1];
                v[2] = (__bf16)acc[i][j][2]; v[3] = (__bf16)acc[i][j][3];
                *(bf16x4*)(Vf + (size_t)(b_ * 8 + h) * 65536 +
                           ((size_t)(((t64 * 4 + ks) * 2 + dhalf) * 64) + hf * 32 + cq) * 8 + jj) = v;
            }
        }
    }
}

// ---------------- flash attention (R11 shell + z16-fold + Pw dbuf) ----------------
// grid: x = 16 (64-row n-tiles), y = 64 (b*h). 128 threads = 2 waves, 32 rows each.
#define FLASH_HALF(T, PWB, KC0, KC1, KN0, KN1)                                         \
  {                                                                                    \
    const int t_ = (T);                                                                \
    const int teB_ = te0 + 2 * t_ + 1;                                                 \
    bf16x8 e1f[4], e2f[4], v0f[4], v1f[4];                                             \
    _Pragma("unroll")                                                                  \
    for (int ks = 0; ks < 4; ++ks) {                                                   \
      e1f[ks] = *(const bf16x8*)(Ef + ((size_t)((teB_ * 4 + ks) * 64) + lane) * 8);    \
      e2f[ks] = *(const bf16x8*)(Ef + ((size_t)(((teB_ + 1) * 4 + ks) * 64) + lane) * 8); \
    }                                                                                  \
    _Pragma("unroll")                                                                  \
    for (int ks = 0; ks < 4; ++ks) {                                                   \
      v0f[ks] = *(const bf16x8*)(Vfb + ((size_t)(((t_ * 4 + ks) * 2 + 0) * 64) + lane) * 8); \
      v1f[ks] = *(const bf16x8*)(Vfb + ((size_t)(((t_ * 4 + ks) * 2 + 1) * 64) + lane) * 8); \
    }                                                                                  \
    f32x16 s0 = __builtin_amdgcn_mfma_f32_32x32x16_bf16(a_q[0], KC0[0], z16, 0, 0, 0); \
    f32x16 s1 = __builtin_amdgcn_mfma_f32_32x32x16_bf16(a_q[0], KC1[0], z16, 0, 0, 0); \
    _Pragma("unroll")                                                                  \
    for (int ks = 1; ks < 4; ++ks) {                                                   \
      s0 = __builtin_amdgcn_mfma_f32_32x32x16_bf16(a_q[ks], KC0[ks], s0, 0, 0, 0);     \
      s1 = __builtin_amdgcn_mfma_f32_32x32x16_bf16(a_q[ks], KC1[ks], s1, 0, 0, 0);     \
    }                                                                                  \
    const int t32n_ = (((T) + 1) & 15) * 2;                                            \
    _Pragma("unroll")                                                                  \
    for (int ks = 0; ks < 4; ++ks) {                                                   \
      KN0[ks] = *(const bf16x8*)(Kfb + ((size_t)((t32n_ * 4 + ks) * 64) + lane) * 8);  \
      KN1[ks] = *(const bf16x8*)(Kfb + ((size_t)(((t32n_ + 1) * 4 + ks) * 64) + lane) * 8); \
    }                                                                                  \
    f32x16 qeB = __builtin_amdgcn_mfma_f32_32x32x16_bf16(a_q[0], e1f[0], z16, 0, 0, 0); \
    f32x16 qeC = __builtin_amdgcn_mfma_f32_32x32x16_bf16(a_q[0], e2f[0], z16, 0, 0, 0); \
    _Pragma("unroll")                                                                  \
    for (int ks = 1; ks < 4; ++ks) {                                                   \
      qeB = __builtin_amdgcn_mfma_f32_32x32x16_bf16(a_q[ks], e1f[ks], qeB, 0, 0, 0);   \
      qeC = __builtin_amdgcn_mfma_f32_32x32x16_bf16(a_q[ks], e2f[ks], qeC, 0, 0, 0);   \
    }                                                                                  \
    _Pragma("unroll")                                                                  \
    for (int r = 0; r < 16; ++r) {                                                     \
      int row = (r & 3) + 8 * (r >> 2) + 4 * half;                                     \
      int tt = colq + 31 - row;                                                        \
      int src = (tt & 31) | (half << 5);                                               \
      float shB = __shfl(qeB[r], src, 64);                                             \
      float shC = __shfl(qeC[r], src, 64);                                             \
      bool sel = (tt >= 32);                                                           \
      float rel0 = sel ? shB : shA[r];                                                 \
      float rel1 = sel ? shC : shB;                                                    \
      float p0 = EXP2(s0[r] + rel0);                                                   \
      float p1 = EXP2(s1[r] + rel1);                                                   \
      rowsum[r] += p0 + p1;                                                            \
      Pw[PWB][w][row][colq]      = (__bf16)p0;                                         \
      Pw[PWB][w][row][32 + colq] = (__bf16)p1;                                         \
      shA[r] = shC;                                                                    \
    }                                                                                  \
    asm volatile("s_waitcnt lgkmcnt(0)" ::: "memory");                                 \
    _Pragma("unroll")                                                                  \
    for (int ks = 0; ks < 4; ++ks) {                                                   \
      bf16x8 pa = *(const bf16x8*)(&Pw[PWB][w][colq][ks * 16 + half * 8]);             \
      o0 = __builtin_amdgcn_mfma_f32_32x32x16_bf16(pa, v0f[ks], o0, 0, 0, 0);          \
      o1 = __builtin_amdgcn_mfma_f32_32x32x16_bf16(pa, v1f[ks], o1, 0, 0, 0);          \
    }                                                                                  \
  }

__global__ __launch_bounds__(128, 2) void flash_kernel(const __bf16* __restrict__ Qb,
                                                       const __bf16* __restrict__ Kf,
                                                       const __bf16* __restrict__ Vf,
                                                       const __bf16* __restrict__ Ef,
                                                       const float* __restrict__ phase,
                                                       __bf16* __restrict__ Ob) {
    const int bh = blockIdx.y;
    const int n0 = blockIdx.x * 64;
    const int w = threadIdx.x >> 6, lane = threadIdx.x & 63;
    const int colq = lane & 31, half = lane >> 5;
    const int nbase = n0 + w * 32;

    __shared__ __bf16 Pw[2][2][32][72];   // double-buffered per-wave P staging

    f32x16 z16;
#pragma unroll
    for (int i = 0; i < 16; ++i) z16[i] = 0.f;

    bf16x8 a_q[4];
#pragma unroll
    for (int ks = 0; ks < 4; ++ks)
        a_q[ks] = *(const bf16x8*)(Qb + ((size_t)bh * 1024 + nbase + colq) * 64 + ks * 16 + half * 8);

    f32x16 o0 = z16, o1 = z16;
    float rowsum[16];
#pragma unroll
    for (int i = 0; i < 16; ++i) rowsum[i] = 0.f;

    const __bf16* Kfb = Kf + (size_t)bh * 65536;
    const __bf16* Vfb = Vf + (size_t)bh * 65536;

    const int te0 = (992 - nbase) >> 5;   // first window tile (>= 0)

    // K double-buffer register sets (t=0 tiles preloaded here)
    bf16x8 kA0[4], kA1[4], kB0[4], kB1[4];
#pragma unroll
    for (int ks = 0; ks < 4; ++ks) {
        kA0[ks] = *(const bf16x8*)(Kfb + ((size_t)((0 * 4 + ks) * 64) + lane) * 8);
        kA1[ks] = *(const bf16x8*)(Kfb + ((size_t)((1 * 4 + ks) * 64) + lane) * 8);
    }

    // prologue: shuffled values of tile te0 (the carried "A" tile)
    float shA[16];
    {
        bf16x8 e0 = *(const bf16x8*)(Ef + ((size_t)((te0 * 4 + 0) * 64) + lane) * 8);
        f32x16 qeA = __builtin_amdgcn_mfma_f32_32x32x16_bf16(a_q[0], e0, z16, 0, 0, 0);
#pragma unroll
        for (int ks = 1; ks < 4; ++ks) {
            bf16x8 e = *(const bf16x8*)(Ef + ((size_t)((te0 * 4 + ks) * 64) + lane) * 8);
            qeA = __builtin_amdgcn_mfma_f32_32x32x16_bf16(a_q[ks], e, qeA, 0, 0, 0);
        }
#pragma unroll
        for (int r = 0; r < 16; ++r) {
            int row = (r & 3) + 8 * (r >> 2) + 4 * half;
            int tt = colq + 31 - row;
            int src = (tt & 31) | (half << 5);
            shA[r] = __shfl(qeA[r], src, 64);
        }
    }

#pragma unroll 1
    for (int tt2 = 0; tt2 < 8; ++tt2) {
        FLASH_HALF(2 * tt2,     0, kA0, kA1, kB0, kB1)
        FLASH_HALF(2 * tt2 + 1, 1, kB0, kB1, kA0, kA1)
    }

    // epilogue: l reduce, scale by phase/l, store via Pw buf 0 for coalescing
    const int b_ = bh >> 3, hh = bh & 7;
#pragma unroll
    for (int r = 0; r < 16; ++r) {
        float l = rowsum[r];
        l += __shfl_xor(l, 1, 32);
        l += __shfl_xor(l, 2, 32);
        l += __shfl_xor(l, 4, 32);
        l += __shfl_xor(l, 8, 32);
        l += __shfl_xor(l, 16, 32);
        int row = (r & 3) + 8 * (r >> 2) + 4 * half;
        float f = phase[(size_t)bh * 1024 + nbase + row] / l;
        Pw[0][w][row][colq]      = (__bf16)(o0[r] * f);
        Pw[0][w][row][32 + colq] = (__bf16)(o1[r] * f);
    }
    asm volatile("s_waitcnt lgkmcnt(0)" ::: "memory");
    {
        int row = lane >> 1, dseg = lane & 1;
        bf16x8 u0 = *(const bf16x8*)(&Pw[0][w][row][dseg * 32]);
        bf16x8 u1 = *(const bf16x8*)(&Pw[0][w][row][dseg * 32 + 8]);
        bf16x8 u2 = *(const bf16x8*)(&Pw[0][w][row][dseg * 32 + 16]);
        bf16x8 u3 = *(const bf16x8*)(&Pw[0][w][row][dseg * 32 + 24]);
        size_t obase = ((size_t)b_ * 1024 + nbase + row) * 512 + hh * 64 + dseg * 32;
        *(bf16x8*)(Ob + obase)      = u0;
        *(bf16x8*)(Ob + obase + 8)  = u1;
        *(bf16x8*)(Ob + obase + 16) = u2;
        *(bf16x8*)(Ob + obase + 24) = u3;
    }
}

// ---------------- output projection GEMM (R11-exact, 128x64 tiles) ----------------
__global__ __launch_bounds__(256) void gemm_out(const __bf16* __restrict__ X,
                                                const __bf16* __restrict__ W,
                                                const float* __restrict__ bo,
                                                float* __restrict__ out) {
    __shared__ __bf16 Xs[128][64];
    __shared__ __bf16 Ws[64][64];
    const int tid = threadIdx.x;
    const int wave = tid >> 6, lane = tid & 63;
    const int col = lane & 15, quad = lane >> 4;
    const int m_base = blockIdx.x * 128;
    const int j_base = blockIdx.y * 64;
    const int wm = (wave & 1) * 64;
    const int wn = (wave >> 1) * 32;
    const f32x4 fz = {0.f, 0.f, 0.f, 0.f};
    f32x4 acc[2][4];
#pragma unroll
    for (int i = 0; i < 2; ++i)
#pragma unroll
        for (int j = 0; j < 4; ++j) acc[i][j] = fz;

    for (int k0 = 0; k0 < 512; k0 += 64) {
#pragma unroll
        for (int p = 0; p < 4; ++p) {
            int s = tid + p * 256;
            int row = s >> 3, cc = (s & 7) * 8;
            GLOAD_LDS16(X + (size_t)(m_base + row) * 512 + k0 + cc, &Xs[0][0] + (size_t)s * 8);
        }
#pragma unroll
        for (int p = 0; p < 2; ++p) {
            int s = tid + p * 256;
            int row = s >> 3, cc = (s & 7) * 8;
            GLOAD_LDS16(W + (size_t)(j_base + row) * 512 + k0 + cc, &Ws[0][0] + (size_t)s * 8);
        }
        __syncthreads();
#pragma unroll
        for (int kk = 0; kk < 64; kk += 32) {
            bf16x8 xa[4], wb[2];
#pragma unroll
            for (int j = 0; j < 4; ++j) xa[j] = *(const bf16x8*)(&Xs[wm + j * 16 + col][kk + quad * 8]);
#pragma unroll
            for (int i = 0; i < 2; ++i) wb[i] = *(const bf16x8*)(&Ws[wn + i * 16 + col][kk + quad * 8]);
#pragma unroll
            for (int i = 0; i < 2; ++i)
#pragma unroll
                for (int j = 0; j < 4; ++j)
                    acc[i][j] = __builtin_amdgcn_mfma_f32_16x16x32_bf16(wb[i], xa[j], acc[i][j], 0, 0, 0);
        }
        __syncthreads();
    }
#pragma unroll
    for (int i = 0; i < 2; ++i) {
#pragma unroll
        for (int j = 0; j < 4; ++j) {
            int jabs = j_base + wn + i * 16 + quad * 4;
            int m = m_base + wm + j * 16 + col;
            f32x4 bv = *(const f32x4*)(bo + jabs);
            f32x4 o = acc[i][j] + bv;
            *(f32x4*)(out + (size_t)m * 512 + jabs) = o;
        }
    }
}

extern "C" void kernel_launch(void* const* d_in, const int* in_sizes, int n_in,
                              void* d_out, int out_size, void* d_ws, size_t ws_size,
                              hipStream_t stream) {
    (void)in_sizes; (void)n_in; (void)out_size; (void)ws_size;
    const float* x     = (const float*)d_in[0];
    const float* phase = (const float*)d_in[1];
    const float* E_rel = (const float*)d_in[2];
    const float* W_q   = (const float*)d_in[3];
    const float* W_k   = (const float*)d_in[4];
    const float* W_v   = (const float*)d_in[5];
    const float* W_o   = (const float*)d_in[6];
    const float* b_o   = (const float*)d_in[7];
    float* out = (float*)d_out;

    char* ws = (char*)d_ws;
    __bf16* xb   = (__bf16*)(ws);                 //  8,388,608 B
    __bf16* wqkv = (__bf16*)(ws + 8388608);       //  1,572,864 B
    __bf16* wob  = (__bf16*)(ws + 9961472);       //    524,288 B
    __bf16* Ef   = (__bf16*)(ws + 10485760);      //    262,144 B fragment stream
    __bf16* Qb   = (__bf16*)(ws + 10747904);      //  8,388,608 B (pre-scaled)
    __bf16* Kf   = (__bf16*)(ws + 19136512);      //  8,388,608 B fragment stream
    __bf16* Vf   = (__bf16*)(ws + 27525120);      //  8,388,608 B fragment stream
    __bf16* Ob   = (__bf16*)(ws + 35913728);      //  8,388,608 B

    cvt_all<<<dim3(5249), dim3(256), 0, stream>>>(x, E_rel, W_q, W_k, W_v, W_o,
                                                  xb, Ef, wqkv, wob);
    gemm_qkv<<<dim3(64, 12), dim3(256), 0, stream>>>(xb, wqkv, Qb, Kf, Vf);
    flash_kernel<<<dim3(16, 64), dim3(128), 0, stream>>>(Qb, Kf, Vf, Ef, phase, Ob);
    gemm_out<<<dim3(64, 8), dim3(256), 0, stream>>>(Ob, wob, b_o, out);
}

// Round 9
// 171.086 us; speedup vs baseline: 3.3390x; 1.0009x over previous
//
#include <hip/hip_runtime.h>

// PhaseMultiHeadAttention: B=8, N=1024, D=512, H=8, dh=64
// R19 = R18 base + flash register-budget lift and E-prefetch:
//   Unified diagnosis of R13/R14/R15/R18: allocator caps this kernel at
//   256/min_waves_arg VGPRs ((128,2)->128, (128,4)->64) and SPILLS under
//   pressure instead of exceeding the cap. HW occupancy is grid-limited
//   at 2 waves/SIMD (1024 blocks), which VGPR<=256 does not reduce, so
//   (128,1) lifts the cap to 256 for free.
//   Spend the headroom: E fragments double-buffered one half ahead
//   (same named-reg pattern as the K dbuf that won R10->R11), and each
//   half streams all 16 QK/QE MFMAs first (operands pre-resident), then
//   issues V(t)/K(t+1)/E(t+1), then shuffle/exp/P-stage, then PV.
//   Math order per value unchanged -> bit-identical output.
// rel[n,m] = Q[n] . E_rel[m-n+N-1]

typedef __bf16 bf16x8 __attribute__((ext_vector_type(8)));
typedef __bf16 bf16x4 __attribute__((ext_vector_type(4)));
typedef float  f32x4  __attribute__((ext_vector_type(4)));
typedef float  f32x16 __attribute__((ext_vector_type(16)));

#if __has_builtin(__builtin_amdgcn_exp2f)
#define EXP2(x) __builtin_amdgcn_exp2f(x)
#else
#define EXP2(x) exp2f(x)
#endif

#define QSCALE 0.18033688011f   // (1/8) * log2(e), folded into Q at projection

// async global->LDS, 16B per lane; LDS dest = wave-uniform base + lane*16
#define GLOAD_LDS16(g, l)                                                      \
    __builtin_amdgcn_global_load_lds(                                          \
        (const __attribute__((address_space(1))) unsigned int*)(g),            \
        (__attribute__((address_space(3))) unsigned int*)(l), 16, 0, 0)

// Fragment-stream layouts (per bh, 65536 elems = 128KB):
//  Kf: [t32 = n>>5][ks = d>>4][lane = ((d>>3)&1)*32 + (n&31)][j = d&7]
//  Vf: [t64 = n>>6][ks = (n>>4)&3][dhalf = d>>5][lane = ((n>>3)&1)*32 + (d&31)][j = n&7]
//  Ef: like Kf over 2048 rows (l = row index): [t32 = l>>5][ks][lane][j]

// ---------------- fused fp32 -> bf16 conversion ----------------
__global__ __launch_bounds__(256) void cvt_all(const float* __restrict__ x,
                                               const float* __restrict__ E,
                                               const float* __restrict__ wq,
                                               const float* __restrict__ wk,
                                               const float* __restrict__ wv,
                                               const float* __restrict__ wo,
                                               __bf16* __restrict__ xb,
                                               __bf16* __restrict__ Ef,
                                               __bf16* __restrict__ wqkv,
                                               __bf16* __restrict__ wob) {
    int i = blockIdx.x * 256 + threadIdx.x;
    if (i >= 1081328 ? i < 1343472 : i < 1048576) {
        const float* s; __bf16* d; int off;
        if      (i < 1048576) { s = x;  d = xb;            off = i; }
        else if (i < 1146864) { s = wq; d = wqkv;          off = i - 1081328; }
        else if (i < 1212400) { s = wk; d = wqkv + 262144; off = i - 1146864; }
        else if (i < 1277936) { s = wv; d = wqkv + 524288; off = i - 1212400; }
        else                  { s = wo; d = wob;           off = i - 1277936; }
        float4 v = *(const float4*)(s + (size_t)off * 4);
        bf16x4 o;
        o[0] = (__bf16)v.x; o[1] = (__bf16)v.y; o[2] = (__bf16)v.z; o[3] = (__bf16)v.w;
        *(bf16x4*)(d + (size_t)off * 4) = o;
    } else if (i >= 1048576 && i < 1081328) {
        // E -> fragment stream
        int off = i - 1048576;
        float4 v = *(const float4*)(E + (size_t)off * 4);
        int e0i = off * 4;
        int l = e0i >> 6, d0 = e0i & 63;
        int t32 = l >> 5, cq = l & 31, ks = d0 >> 4, hf = (d0 >> 3) & 1, j = d0 & 7;
        bf16x4 o;
        o[0] = (__bf16)v.x; o[1] = (__bf16)v.y; o[2] = (__bf16)v.z; o[3] = (__bf16)v.w;
        *(bf16x4*)(Ef + ((size_t)((t32 * 4 + ks) * 64) + hf * 32 + cq) * 8 + j) = o;
    }
}

// ---------------- QKV projection GEMM (R11-exact) ----------------
__global__ __launch_bounds__(256) void gemm_qkv(const __bf16* __restrict__ X,
                                                const __bf16* __restrict__ W,
                                                __bf16* __restrict__ Qb,
                                                __bf16* __restrict__ Kf,
                                                __bf16* __restrict__ Vf) {
    __shared__ __bf16 Xs[128][64];
    __shared__ __bf16 Ws[128][64];
    const int tid = threadIdx.x;
    const int wave = tid >> 6, lane = tid & 63;
    const int col = lane & 15, quad = lane >> 4;
    const int m_base = blockIdx.x * 128;
    const int j_base = blockIdx.y * 128;
    const bool qk = (j_base < 1024);
    const int wm = (wave & 1) * 64;
    const int wn = (wave >> 1) * 64;
    const f32x4 fz = {0.f, 0.f, 0.f, 0.f};
    f32x4 acc[4][4];
#pragma unroll
    for (int i = 0; i < 4; ++i)
#pragma unroll
        for (int j = 0; j < 4; ++j) acc[i][j] = fz;

    for (int k0 = 0; k0 < 512; k0 += 64) {
#pragma unroll
        for (int p = 0; p < 4; ++p) {
            int s = tid + p * 256;
            int row = s >> 3, cc = (s & 7) * 8;
            GLOAD_LDS16(X + (size_t)(m_base + row) * 512 + k0 + cc, &Xs[0][0] + (size_t)s * 8);
            GLOAD_LDS16(W + (size_t)(j_base + row) * 512 + k0 + cc, &Ws[0][0] + (size_t)s * 8);
        }
        __syncthreads();
#pragma unroll
        for (int kk = 0; kk < 64; kk += 32) {
            bf16x8 xa[4], wb[4];
#pragma unroll
            for (int i = 0; i < 4; ++i) xa[i] = *(const bf16x8*)(&Xs[wm + i * 16 + col][kk + quad * 8]);
#pragma unroll
            for (int j = 0; j < 4; ++j) wb[j] = *(const bf16x8*)(&Ws[wn + j * 16 + col][kk + quad * 8]);
            if (qk) {
#pragma unroll
                for (int i = 0; i < 4; ++i)
#pragma unroll
                    for (int j = 0; j < 4; ++j)
                        acc[i][j] = __builtin_amdgcn_mfma_f32_16x16x32_bf16(wb[i], xa[j], acc[i][j], 0, 0, 0);
            } else {
#pragma unroll
                for (int i = 0; i < 4; ++i)
#pragma unroll
                    for (int j = 0; j < 4; ++j)
                        acc[i][j] = __builtin_amdgcn_mfma_f32_16x16x32_bf16(xa[i], wb[j], acc[i][j], 0, 0, 0);
            }
        }
        __syncthreads();
    }
    if (qk) {
#pragma unroll
        for (int i = 0; i < 4; ++i) {
#pragma unroll
            for (int j = 0; j < 4; ++j) {
                int jabs = j_base + wn + i * 16 + quad * 4;
                int m = m_base + wm + j * 16 + col;
                int b_ = m >> 10, n = m & 1023;
                int rem = jabs & 511, h = rem >> 6, d = rem & 63;
                bf16x4 v;
                if (jabs < 512) {
                    v[0] = (__bf16)(acc[i][j][0] * QSCALE);
                    v[1] = (__bf16)(acc[i][j][1] * QSCALE);
                    v[2] = (__bf16)(acc[i][j][2] * QSCALE);
                    v[3] = (__bf16)(acc[i][j][3] * QSCALE);
                    *(bf16x4*)(Qb + (((size_t)b_ * 8 + h) * 1024 + n) * 64 + d) = v;
                } else {
                    v[0] = (__bf16)acc[i][j][0]; v[1] = (__bf16)acc[i][j][1];
                    v[2] = (__bf16)acc[i][j][2]; v[3] = (__bf16)acc[i][j][3];
                    int t32 = n >> 5, cq = n & 31, ks = d >> 4, hf = (d >> 3) & 1, jj = d & 7;
                    *(bf16x4*)(Kf + (size_t)(b_ * 8 + h) * 65536 +
                               ((size_t)((t32 * 4 + ks) * 64) + hf * 32 + cq) * 8 + jj) = v;
                }
            }
        }
    } else {
#pragma unroll
        for (int i = 0; i < 4; ++i) {
#pragma unroll
            for (int j = 0; j < 4; ++j) {
                int m = m_base + wm + i * 16 + quad * 4;
                int b_ = m >> 10, n = m & 1023;
                int jabs = j_base + wn + j * 16 + col;
                int rem = jabs & 511, h = rem >> 6, d = rem & 63;
                int t64 = n >> 6, ks = (n >> 4) & 3, hf = (n >> 3) & 1, jj = n & 7;
                int dhalf = d >> 5, cq = d & 31;
                bf16x4 v;
                v[0] = (__bf16)acc[i][j][0]; v[1] = (__bf16)acc[i][j][1];
                v[2] = (__bf16)acc[i][j][2]; v[3] = (__bf16)acc[i][j][3];
                *(bf16x4*)(Vf + (size_t)(b_ * 8 + h) * 65536 +
                           ((size_t)(((t64 * 4 + ks) * 2 + dhalf) * 64) + hf * 32 + cq) * 8 + jj) = v;
            }
        }
    }
}

// ---------------- flash attention (R18 shell + (128,1) + E dbuf prefetch) ----------------
// grid: x = 16 (64-row n-tiles), y = 64 (b*h). 128 threads = 2 waves, 32 rows each.
#define FLASH_HALF(T, PWB, KC0, KC1, KN0, KN1, EC1, EC2, EN1, EN2)                     \
  {                                                                                    \
    const int t_ = (T);                                                                \
    /* all 16 QK/QE MFMAs stream first: K and E operands are pre-resident */           \
    f32x16 s0 = __builtin_amdgcn_mfma_f32_32x32x16_bf16(a_q[0], KC0[0], z16, 0, 0, 0); \
    f32x16 s1 = __builtin_amdgcn_mfma_f32_32x32x16_bf16(a_q[0], KC1[0], z16, 0, 0, 0); \
    _Pragma("unroll")                                                                  \
    for (int ks = 1; ks < 4; ++ks) {                                                   \
      s0 = __builtin_amdgcn_mfma_f32_32x32x16_bf16(a_q[ks], KC0[ks], s0, 0, 0, 0);     \
      s1 = __builtin_amdgcn_mfma_f32_32x32x16_bf16(a_q[ks], KC1[ks], s1, 0, 0, 0);     \
    }                                                                                  \
    f32x16 qeB = __builtin_amdgcn_mfma_f32_32x32x16_bf16(a_q[0], EC1[0], z16, 0, 0, 0); \
    f32x16 qeC = __builtin_amdgcn_mfma_f32_32x32x16_bf16(a_q[0], EC2[0], z16, 0, 0, 0); \
    _Pragma("unroll")                                                                  \
    for (int ks = 1; ks < 4; ++ks) {                                                   \
      qeB = __builtin_amdgcn_mfma_f32_32x32x16_bf16(a_q[ks], EC1[ks], qeB, 0, 0, 0);   \
      qeC = __builtin_amdgcn_mfma_f32_32x32x16_bf16(a_q[ks], EC2[ks], qeC, 0, 0, 0);   \
    }                                                                                  \
    /* issue loads: V for this half, K/E for the next half */                          \
    bf16x8 v0f[4], v1f[4];                                                             \
    _Pragma("unroll")                                                                  \
    for (int ks = 0; ks < 4; ++ks) {                                                   \
      v0f[ks] = *(const bf16x8*)(Vfb + ((size_t)(((t_ * 4 + ks) * 2 + 0) * 64) + lane) * 8); \
      v1f[ks] = *(const bf16x8*)(Vfb + ((size_t)(((t_ * 4 + ks) * 2 + 1) * 64) + lane) * 8); \
    }                                                                                  \
    const int t32n_ = (((T) + 1) & 15) * 2;                                            \
    _Pragma("unroll")                                                                  \
    for (int ks = 0; ks < 4; ++ks) {                                                   \
      KN0[ks] = *(const bf16x8*)(Kfb + ((size_t)((t32n_ * 4 + ks) * 64) + lane) * 8);  \
      KN1[ks] = *(const bf16x8*)(Kfb + ((size_t)(((t32n_ + 1) * 4 + ks) * 64) + lane) * 8); \
    }                                                                                  \
    const int teN1_ = (te0 + 2 * t_ + 3) & 63;                                         \
    const int teN2_ = (te0 + 2 * t_ + 4) & 63;                                         \
    _Pragma("unroll")                                                                  \
    for (int ks = 0; ks < 4; ++ks) {                                                   \
      EN1[ks] = *(const bf16x8*)(Ef + ((size_t)((teN1_ * 4 + ks) * 64) + lane) * 8);   \
      EN2[ks] = *(const bf16x8*)(Ef + ((size_t)((teN2_ * 4 + ks) * 64) + lane) * 8);   \
    }                                                                                  \
    /* skew shuffle + exp + P staging (math order unchanged) */                        \
    _Pragma("unroll")                                                                  \
    for (int r = 0; r < 16; ++r) {                                                     \
      int row = (r & 3) + 8 * (r >> 2) + 4 * half;                                     \
      int tt = colq + 31 - row;                                                        \
      int src = (tt & 31) | (half << 5);                                               \
      float shB = __shfl(qeB[r], src, 64);                                             \
      float shC = __shfl(qeC[r], src, 64);                                             \
      bool sel = (tt >= 32);                                                           \
      float rel0 = sel ? shB : shA[r];                                                 \
      float rel1 = sel ? shC : shB;                                                    \
      float p0 = EXP2(s0[r] + rel0);                                                   \
      float p1 = EXP2(s1[r] + rel1);                                                   \
      rowsum[r] += p0 + p1;                                                            \
      Pw[PWB][w][row][colq]      = (__bf16)p0;                                         \
      Pw[PWB][w][row][32 + colq] = (__bf16)p1;                                         \
      shA[r] = shC;                                                                    \
    }                                                                                  \
    asm volatile("s_waitcnt lgkmcnt(0)" ::: "memory");                                 \
    _Pragma("unroll")                                                                  \
    for (int ks = 0; ks < 4; ++ks) {                                                   \
      bf16x8 pa = *(const bf16x8*)(&Pw[PWB][w][colq][ks * 16 + half * 8]);             \
      o0 = __builtin_amdgcn_mfma_f32_32x32x16_bf16(pa, v0f[ks], o0, 0, 0, 0);          \
      o1 = __builtin_amdgcn_mfma_f32_32x32x16_bf16(pa, v1f[ks], o1, 0, 0, 0);          \
    }                                                                                  \
  }

__global__ __launch_bounds__(128, 1) void flash_kernel(const __bf16* __restrict__ Qb,
                                                       const __bf16* __restrict__ Kf,
                                                       const __bf16* __restrict__ Vf,
                                                       const __bf16* __restrict__ Ef,
                                                       const float* __restrict__ phase,
                                                       __bf16* __restrict__ Ob) {
    const int bh = blockIdx.y;
    const int n0 = blockIdx.x * 64;
    const int w = threadIdx.x >> 6, lane = threadIdx.x & 63;
    const int colq = lane & 31, half = lane >> 5;
    const int nbase = n0 + w * 32;

    __shared__ __bf16 Pw[2][2][32][72];   // double-buffered per-wave P staging

    f32x16 z16;
#pragma unroll
    for (int i = 0; i < 16; ++i) z16[i] = 0.f;

    bf16x8 a_q[4];
#pragma unroll
    for (int ks = 0; ks < 4; ++ks)
        a_q[ks] = *(const bf16x8*)(Qb + ((size_t)bh * 1024 + nbase + colq) * 64 + ks * 16 + half * 8);

    f32x16 o0 = z16, o1 = z16;
    float rowsum[16];
#pragma unroll
    for (int i = 0; i < 16; ++i) rowsum[i] = 0.f;

    const __bf16* Kfb = Kf + (size_t)bh * 65536;
    const __bf16* Vfb = Vf + (size_t)bh * 65536;

    const int te0 = (992 - nbase) >> 5;   // first window tile (>= 0)

    // K + E double-buffer register sets (t=0 operands preloaded here)
    bf16x8 kA0[4], kA1[4], kB0[4], kB1[4];
    bf16x8 eA1[4], eA2[4], eB1[4], eB2[4];
#pragma unroll
    for (int ks = 0; ks < 4; ++ks) {
        kA0[ks] = *(const bf16x8*)(Kfb + ((size_t)((0 * 4 + ks) * 64) + lane) * 8);
        kA1[ks] = *(const bf16x8*)(Kfb + ((size_t)((1 * 4 + ks) * 64) + lane) * 8);
        eA1[ks] = *(const bf16x8*)(Ef + ((size_t)(((te0 + 1) * 4 + ks) * 64) + lane) * 8);
        eA2[ks] = *(const bf16x8*)(Ef + ((size_t)(((te0 + 2) * 4 + ks) * 64) + lane) * 8);
    }

    // prologue: shuffled values of tile te0 (the carried "A" tile)
    float shA[16];
    {
        bf16x8 e0 = *(const bf16x8*)(Ef + ((size_t)((te0 * 4 + 0) * 64) + lane) * 8);
        f32x16 qeA = __builtin_amdgcn_mfma_f32_32x32x16_bf16(a_q[0], e0, z16, 0, 0, 0);
#pragma unroll
        for (int ks = 1; ks < 4; ++ks) {
            bf16x8 e = *(const bf16x8*)(Ef + ((size_t)((te0 * 4 + ks) * 64) + lane) * 8);
            qeA = __builtin_amdgcn_mfma_f32_32x32x16_bf16(a_q[ks], e, qeA, 0, 0, 0);
        }
#pragma unroll
        for (int r = 0; r < 16; ++r) {
            int row = (r & 3) + 8 * (r >> 2) + 4 * half;
            int tt = colq + 31 - row;
            int src = (tt & 31) | (half << 5);
            shA[r] = __shfl(qeA[r], src, 64);
        }
    }

#pragma unroll 1
    for (int tt2 = 0; tt2 < 8; ++tt2) {
        FLASH_HALF(2 * tt2,     0, kA0, kA1, kB0, kB1, eA1, eA2, eB1, eB2)
        FLASH_HALF(2 * tt2 + 1, 1, kB0, kB1, kA0, kA1, eB1, eB2, eA1, eA2)
    }

    // epilogue: l reduce, scale by phase/l, store via Pw buf 0 for coalescing
    const int b_ = bh >> 3, hh = bh & 7;
#pragma unroll
    for (int r = 0; r < 16; ++r) {
        float l = rowsum[r];
        l += __shfl_xor(l, 1, 32);
        l += __shfl_xor(l, 2, 32);
        l += __shfl_xor(l, 4, 32);
        l += __shfl_xor(l, 8, 32);
        l += __shfl_xor(l, 16, 32);
        int row = (r & 3) + 8 * (r >> 2) + 4 * half;
        float f = phase[(size_t)bh * 1024 + nbase + row] / l;
        Pw[0][w][row][colq]      = (__bf16)(o0[r] * f);
        Pw[0][w][row][32 + colq] = (__bf16)(o1[r] * f);
    }
    asm volatile("s_waitcnt lgkmcnt(0)" ::: "memory");
    {
        int row = lane >> 1, dseg = lane & 1;
        bf16x8 u0 = *(const bf16x8*)(&Pw[0][w][row][dseg * 32]);
        bf16x8 u1 = *(const bf16x8*)(&Pw[0][w][row][dseg * 32 + 8]);
        bf16x8 u2 = *(const bf16x8*)(&Pw[0][w][row][dseg * 32 + 16]);
        bf16x8 u3 = *(const bf16x8*)(&Pw[0][w][row][dseg * 32 + 24]);
        size_t obase = ((size_t)b_ * 1024 + nbase + row) * 512 + hh * 64 + dseg * 32;
        *(bf16x8*)(Ob + obase)      = u0;
        *(bf16x8*)(Ob + obase + 8)  = u1;
        *(bf16x8*)(Ob + obase + 16) = u2;
        *(bf16x8*)(Ob + obase + 24) = u3;
    }
}

// ---------------- output projection GEMM (R11-exact, 128x64 tiles) ----------------
__global__ __launch_bounds__(256) void gemm_out(const __bf16* __restrict__ X,
                                                const __bf16* __restrict__ W,
                                                const float* __restrict__ bo,
                                                float* __restrict__ out) {
    __shared__ __bf16 Xs[128][64];
    __shared__ __bf16 Ws[64][64];
    const int tid = threadIdx.x;
    const int wave = tid >> 6, lane = tid & 63;
    const int col = lane & 15, quad = lane >> 4;
    const int m_base = blockIdx.x * 128;
    const int j_base = blockIdx.y * 64;
    const int wm = (wave & 1) * 64;
    const int wn = (wave >> 1) * 32;
    const f32x4 fz = {0.f, 0.f, 0.f, 0.f};
    f32x4 acc[2][4];
#pragma unroll
    for (int i = 0; i < 2; ++i)
#pragma unroll
        for (int j = 0; j < 4; ++j) acc[i][j] = fz;

    for (int k0 = 0; k0 < 512; k0 += 64) {
#pragma unroll
        for (int p = 0; p < 4; ++p) {
            int s = tid + p * 256;
            int row = s >> 3, cc = (s & 7) * 8;
            GLOAD_LDS16(X + (size_t)(m_base + row) * 512 + k0 + cc, &Xs[0][0] + (size_t)s * 8);
        }
#pragma unroll
        for (int p = 0; p < 2; ++p) {
            int s = tid + p * 256;
            int row = s >> 3, cc = (s & 7) * 8;
            GLOAD_LDS16(W + (size_t)(j_base + row) * 512 + k0 + cc, &Ws[0][0] + (size_t)s * 8);
        }
        __syncthreads();
#pragma unroll
        for (int kk = 0; kk < 64; kk += 32) {
            bf16x8 xa[4], wb[2];
#pragma unroll
            for (int j = 0; j < 4; ++j) xa[j] = *(const bf16x8*)(&Xs[wm + j * 16 + col][kk + quad * 8]);
#pragma unroll
            for (int i = 0; i < 2; ++i) wb[i] = *(const bf16x8*)(&Ws[wn + i * 16 + col][kk + quad * 8]);
#pragma unroll
            for (int i = 0; i < 2; ++i)
#pragma unroll
                for (int j = 0; j < 4; ++j)
                    acc[i][j] = __builtin_amdgcn_mfma_f32_16x16x32_bf16(wb[i], xa[j], acc[i][j], 0, 0, 0);
        }
        __syncthreads();
    }
#pragma unroll
    for (int i = 0; i < 2; ++i) {
#pragma unroll
        for (int j = 0; j < 4; ++j) {
            int jabs = j_base + wn + i * 16 + quad * 4;
            int m = m_base + wm + j * 16 + col;
            f32x4 bv = *(const f32x4*)(bo + jabs);
            f32x4 o = acc[i][j] + bv;
            *(f32x4*)(out + (size_t)m * 512 + jabs) = o;
        }
    }
}

extern "C" void kernel_launch(void* const* d_in, const int* in_sizes, int n_in,
                              void* d_out, int out_size, void* d_ws, size_t ws_size,
                              hipStream_t stream) {
    (void)in_sizes; (void)n_in; (void)out_size; (void)ws_size;
    const float* x     = (const float*)d_in[0];
    const float* phase = (const float*)d_in[1];
    const float* E_rel = (const float*)d_in[2];
    const float* W_q   = (const float*)d_in[3];
    const float* W_k   = (const float*)d_in[4];
    const float* W_v   = (const float*)d_in[5];
    const float* W_o   = (const float*)d_in[6];
    const float* b_o   = (const float*)d_in[7];
    float* out = (float*)d_out;

    char* ws = (char*)d_ws;
    __bf16* xb   = (__bf16*)(ws);                 //  8,388,608 B
    __bf16* wqkv = (__bf16*)(ws + 8388608);       //  1,572,864 B
    __bf16* wob  = (__bf16*)(ws + 9961472);       //    524,288 B
    __bf16* Ef   = (__bf16*)(ws + 10485760);      //    262,144 B fragment stream
    __bf16* Qb   = (__bf16*)(ws + 10747904);      //  8,388,608 B (pre-scaled)
    __bf16* Kf   = (__bf16*)(ws + 19136512);      //  8,388,608 B fragment stream
    __bf16* Vf   = (__bf16*)(ws + 27525120);      //  8,388,608 B fragment stream
    __bf16* Ob   = (__bf16*)(ws + 35913728);      //  8,388,608 B

    cvt_all<<<dim3(5249), dim3(256), 0, stream>>>(x, E_rel, W_q, W_k, W_v, W_o,
                                                  xb, Ef, wqkv, wob);
    gemm_qkv<<<dim3(64, 12), dim3(256), 0, stream>>>(xb, wqkv, Qb, Kf, Vf);
    flash_kernel<<<dim3(16, 64), dim3(128), 0, stream>>>(Qb, Kf, Vf, Ef, phase, Ob);
    gemm_out<<<dim3(64, 8), dim3(256), 0, stream>>>(Ob, wob, b_o, out);
}